// Round 11
// baseline (784.697 us; speedup 1.0000x reference)
//
#include <hip/hip_runtime.h>
#include <math.h>

#define LL 2048
#define MM 12
#define DD 128
#define TP 256   // T

typedef short short8 __attribute__((ext_vector_type(8)));
typedef short short4v __attribute__((ext_vector_type(4)));
typedef float float4v __attribute__((ext_vector_type(4)));

static __device__ __forceinline__ unsigned short f2b(float f) {
  union { float f; unsigned int u; } x; x.f = f;
  unsigned int r = x.u + 0x7fffu + ((x.u >> 16) & 1u);
  return (unsigned short)(r >> 16);
}
static __device__ __forceinline__ float b2f(unsigned short u) {
  union { unsigned int u; float f; } x; x.u = ((unsigned int)u) << 16;
  return x.f;
}
static __device__ __forceinline__ float qxor1(float x) {
  int r = __builtin_amdgcn_mov_dpp(__builtin_bit_cast(int, x), 0xB1, 0xF, 0xF, true);
  return __builtin_bit_cast(float, r);
}
static __device__ __forceinline__ float qxor2(float x) {
  int r = __builtin_amdgcn_mov_dpp(__builtin_bit_cast(int, x), 0x4E, 0xF, 0xF, true);
  return __builtin_bit_cast(float, r);
}

// ---------------- convert all fp32 weights to bf16 (pw, in_w, out_w, padded xp_w, padded ew) ----------------
__global__ __launch_bounds__(256) void k_cvt(const float* __restrict__ pw_w, const float* __restrict__ in_w,
                                             const float* __restrict__ out_w, const float* __restrict__ xp_w,
                                             const float* __restrict__ ew,
                                             unsigned short* __restrict__ pwbf) {
  int i = blockIdx.x * 256 + threadIdx.x;
  if (i < 49152) { pwbf[i] = f2b(pw_w[i]); return; }
  int i2 = i - 49152;
  if (i2 < 131072) { pwbf[i] = f2b(in_w[i2]); return; }
  int i3 = i2 - 131072;
  if (i3 < 65536) { pwbf[i] = f2b(out_w[i3]); return; }
  int i4 = i3 - 65536;
  if (i4 < 24576) {
    int layer = (i4 < 12288) ? 0 : 1;
    int rem = i4 - layer * 12288;
    int k = rem >> 8, c = rem & 255;
    float v = (k < 40) ? xp_w[layer * 10240 + k * 256 + c] : 0.0f;
    pwbf[i] = f2b(v);
    return;
  }
  int i5 = i4 - 24576;
  if (i5 < 4096) {   // ew padded [128][32], zeros for k>=16
    int d = i5 >> 5, k = i5 & 31;
    float v = (k < 16) ? ew[d * 16 + k] : 0.0f;
    pwbf[i] = f2b(v);
  }
}

// ---------------- embedding via MFMA: strided conv1d = 128x256x16 GEMM per sig ----------------
__global__ __launch_bounds__(256) void k_emb(const float* __restrict__ inp,
                                             const unsigned short* __restrict__ ewbf,  // [128][32] bf16
                                             const float* __restrict__ eb,
                                             unsigned short* __restrict__ xe) {
  int sig = blockIdx.x;
  int b = sig / MM, m = sig % MM;
  __shared__ float xs[LL];
  const float* ib = inp + (size_t)b * LL * MM + m;
  int tid = threadIdx.x;
  for (int i = tid; i < LL; i += 256) xs[i] = ib[(size_t)i * MM];
  __syncthreads();
  int wv = tid >> 6, ln = tid & 15, q = (tid >> 4) & 3;
  short8 af[8];
#pragma unroll
  for (int et = 0; et < 8; ++et)
    af[et] = *(const short8*)(ewbf + (et * 16 + ln) * 32 + q * 8);
#pragma unroll
  for (int pass = 0; pass < 4; ++pass) {
    int t = pass * 64 + wv * 16 + ln;
    int l0 = t * 8 - 4;
    short8 bfrag;
#pragma unroll
    for (int j = 0; j < 8; ++j) {
      int k = q * 8 + j;
      int l = l0 + k;
      float v = (k < 16 && l >= 0 && l < LL) ? xs[l] : 0.0f;
      bfrag[j] = (short)f2b(v);
    }
    float4v acc[8];
#pragma unroll
    for (int et = 0; et < 8; ++et) {
      acc[et] = (float4v){0.f, 0.f, 0.f, 0.f};
      acc[et] = __builtin_amdgcn_mfma_f32_16x16x32_bf16(af[et], bfrag, acc[et], 0, 0, 0);
    }
    unsigned short* orow = xe + (size_t)sig * 32768 + (size_t)t * 128;
#pragma unroll
    for (int et = 0; et < 8; ++et) {
      int e = et * 16 + q * 4;
      float4 pb = *(const float4*)&eb[e];
      short4v st = {(short)f2b(acc[et][0] + pb.x), (short)f2b(acc[et][1] + pb.y),
                    (short)f2b(acc[et][2] + pb.z), (short)f2b(acc[et][3] + pb.w)};
      *(short4v*)(orow + e) = st;
    }
  }
}

// ---------------- fused block, [sig][t][d]; single-LDS two-phase v overlay ----------------
template<int UPD>
__global__ __launch_bounds__(256) void k_blk(const unsigned short* __restrict__ uin,
                                             const unsigned short* __restrict__ win,
                                             const float* __restrict__ abuf,
                                             const float* __restrict__ dww, const float* __restrict__ dwb,
                                             const unsigned short* __restrict__ pwbf,
                                             const float* __restrict__ pwb,
                                             unsigned short* __restrict__ uout,
                                             unsigned short* __restrict__ wout) {
  __shared__ unsigned short us[68 * 136];

  int sig = blockIdx.x >> 2;
  int t0 = (blockIdx.x & 3) * 64;
  int tid = threadIdx.x;
  const size_t gbase = (size_t)sig * 32768;
  int c8 = (tid & 15) * 8;

  float aloc[8];
  if (UPD) {
    float4 a0 = *(const float4*)&abuf[sig * 128 + c8];
    float4 a1 = *(const float4*)&abuf[sig * 128 + c8 + 4];
    aloc[0] = a0.x; aloc[1] = a0.y; aloc[2] = a0.z; aloc[3] = a0.w;
    aloc[4] = a1.x; aloc[5] = a1.y; aloc[6] = a1.z; aloc[7] = a1.w;
  }

  const short8 ZV = {0, 0, 0, 0, 0, 0, 0, 0};
#pragma unroll
  for (int it = 0; it < 5; ++it) {
    int idx = it * 256 + tid;
    if (idx < 1088) {
      int row = idx >> 4;
      int t = t0 - 2 + row;
      short8 u8 = ZV;
      if (t >= 0 && t < TP) {
        u8 = *(const short8*)(uin + gbase + (size_t)t * 128 + c8);
        if (UPD) {
          short8 w8 = *(const short8*)(win + gbase + (size_t)t * 128 + c8);
          short8 r;
#pragma unroll
          for (int j = 0; j < 8; ++j)
            r[j] = (short)f2b(b2f((unsigned short)u8[j]) + b2f((unsigned short)w8[j]) * aloc[j]);
          u8 = r;
          if (row >= 2 && row < 66)
            *(short8*)(uout + gbase + (size_t)(t0 + row - 2) * 128 + c8) = u8;
        }
      }
      *(short8*)(us + row * 136 + c8) = u8;
    }
  }
  __syncthreads();

  float wl[5][8], bl[8];
#pragma unroll
  for (int j = 0; j < 8; ++j) {
    bl[j] = dwb[c8 + j];
#pragma unroll
    for (int k = 0; k < 5; ++k) wl[k][j] = dww[(c8 + j) * 5 + k];
  }

  int r0 = tid >> 4;
  short8 vv[2];
#pragma unroll
  for (int s = 0; s < 2; ++s) {
    int i = r0 + s * 16;
    float acc[8];
#pragma unroll
    for (int j = 0; j < 8; ++j) acc[j] = bl[j];
#pragma unroll
    for (int k = 0; k < 5; ++k) {
      short8 u8 = *(const short8*)(us + (i + k) * 136 + c8);
#pragma unroll
      for (int j = 0; j < 8; ++j) acc[j] += b2f((unsigned short)u8[j]) * wl[k][j];
    }
#pragma unroll
    for (int j = 0; j < 8; ++j)
      vv[s][j] = (short)f2b(0.5f * acc[j] * (1.0f + erff(acc[j] * 0.70710678118654752f)));
  }
  __syncthreads();
#pragma unroll
  for (int s = 0; s < 2; ++s)
    *(short8*)(us + (r0 + s * 16) * 136 + c8) = vv[s];

#pragma unroll
  for (int s = 0; s < 2; ++s) {
    int i = 32 + r0 + s * 16;
    float acc[8];
#pragma unroll
    for (int j = 0; j < 8; ++j) acc[j] = bl[j];
#pragma unroll
    for (int k = 0; k < 5; ++k) {
      short8 u8 = *(const short8*)(us + (i + k) * 136 + c8);
#pragma unroll
      for (int j = 0; j < 8; ++j) acc[j] += b2f((unsigned short)u8[j]) * wl[k][j];
    }
#pragma unroll
    for (int j = 0; j < 8; ++j)
      vv[s][j] = (short)f2b(0.5f * acc[j] * (1.0f + erff(acc[j] * 0.70710678118654752f)));
  }
  __syncthreads();
#pragma unroll
  for (int s = 0; s < 2; ++s)
    *(short8*)(us + (32 + r0 + s * 16) * 136 + c8) = vv[s];
  __syncthreads();

  int wv = tid >> 6;
  int ln = tid & 15;
  int q  = (tid >> 4) & 3;
  int tw = wv * 16;
  float4v acc4[8];
#pragma unroll
  for (int et = 0; et < 8; ++et) acc4[et] = (float4v){0.f, 0.f, 0.f, 0.f};
#pragma unroll
  for (int kc = 0; kc < 4; ++kc) {
    int d0 = kc * 32;
    short8 bfrag = *(const short8*)(us + (tw + ln) * 136 + d0 + q * 8);
#pragma unroll
    for (int et = 0; et < 8; ++et) {
      short8 af = *(const short8*)(pwbf + (size_t)(et * 16 + ln) * 128 + d0 + q * 8);
      acc4[et] = __builtin_amdgcn_mfma_f32_16x16x32_bf16(af, bfrag, acc4[et], 0, 0, 0);
    }
  }

  int tg = t0 + tw + ln;
#pragma unroll
  for (int et = 0; et < 8; ++et) {
    int e = et * 16 + q * 4;
    float4 pb = *(const float4*)&pwb[e];
    short4v st = {(short)f2b(acc4[et][0] + pb.x), (short)f2b(acc4[et][1] + pb.y),
                  (short)f2b(acc4[et][2] + pb.z), (short)f2b(acc4[et][3] + pb.w)};
    *(short4v*)(wout + gbase + (size_t)tg * 128 + e) = st;
  }
}

// ---------------- SE gate: sum W over t (cache-warm) + two matvecs ----------------
__global__ __launch_bounds__(256) void k_se(const unsigned short* __restrict__ W,
                                            const float* __restrict__ w1, const float* __restrict__ b1,
                                            const float* __restrict__ w2, const float* __restrict__ b2,
                                            float* __restrict__ abuf) {
  int sig = blockIdx.x;
  __shared__ float part[4][130];
  __shared__ float sm[128];
  __shared__ float hh[32];
  int tid = threadIdx.x;
  int dq = (tid & 63) * 2;
  int quarter = tid >> 6;
  const unsigned short* Wp = W + (size_t)sig * 32768 + (size_t)quarter * 64 * 128;
  float s0 = 0.f, s1 = 0.f;
#pragma unroll 4
  for (int t = 0; t < 64; ++t) {
    ushort2 v = *(const ushort2*)&Wp[t * 128 + dq];
    s0 += b2f(v.x); s1 += b2f(v.y);
  }
  part[quarter][dq] = s0;
  part[quarter][dq + 1] = s1;
  __syncthreads();
  if (tid < 128) sm[tid] = (part[0][tid] + part[1][tid] + part[2][tid] + part[3][tid]) * (1.0f / 256.0f);
  __syncthreads();
  if (tid < 32) {
    float acc = b1[tid];
    for (int d = 0; d < 128; ++d) acc += w1[tid * 128 + d] * sm[d];
    hh[tid] = fmaxf(acc, 0.0f);
  }
  __syncthreads();
  if (tid < 128) {
    float acc = b2[tid];
#pragma unroll
    for (int r = 0; r < 32; ++r) acc += w2[tid * 32 + r] * hh[r];
    abuf[sig * 128 + tid] = 1.0f / (1.0f + expf(-acc));
  }
}

// ---------------- final update + mean over M -> xe2 fp32 + xe2bf bf16 ----------------
__global__ __launch_bounds__(256) void k_reduce2(const unsigned short* __restrict__ u,
                                                 const unsigned short* __restrict__ w,
                                                 const float* __restrict__ abuf, float* __restrict__ xe2,
                                                 unsigned short* __restrict__ xe2bf) {
  int i = blockIdx.x * 256 + threadIdx.x;
  int d0 = (i & 15) * 8;
  int t = (i >> 4) & 255;
  int b = i >> 12;
  float acc[8] = {0.f, 0.f, 0.f, 0.f, 0.f, 0.f, 0.f, 0.f};
#pragma unroll 4
  for (int m = 0; m < 12; ++m) {
    size_t base = ((size_t)(b * 12 + m) * 256 + t) * 128 + d0;
    short8 u8 = *(const short8*)(u + base);
    short8 w8 = *(const short8*)(w + base);
    float4 a0 = *(const float4*)&abuf[(b * 12 + m) * 128 + d0];
    float4 a1 = *(const float4*)&abuf[(b * 12 + m) * 128 + d0 + 4];
    float av[8] = {a0.x, a0.y, a0.z, a0.w, a1.x, a1.y, a1.z, a1.w};
#pragma unroll
    for (int j = 0; j < 8; ++j)
      acc[j] += b2f((unsigned short)u8[j]) + b2f((unsigned short)w8[j]) * av[j];
  }
  size_t off = (size_t)b * 32768 + (size_t)t * 128 + d0;
  float4 o0 = {acc[0] / 12.f, acc[1] / 12.f, acc[2] / 12.f, acc[3] / 12.f};
  float4 o1 = {acc[4] / 12.f, acc[5] / 12.f, acc[6] / 12.f, acc[7] / 12.f};
  *(float4*)(xe2 + off) = o0;
  *(float4*)(xe2 + off + 4) = o1;
  short8 ob;
#pragma unroll
  for (int j = 0; j < 8; ++j) ob[j] = (short)f2b(acc[j] / 12.f);
  *(short8*)(xe2bf + off) = ob;
}

// ---------------- mamba: in-projection via MFMA, zero-LDS -> bf16 xz[t][e] ----------------
__global__ __launch_bounds__(256) void k_inproj(const unsigned short* __restrict__ xe2bf,
                                                const unsigned short* __restrict__ inwbf,
                                                unsigned short* __restrict__ xz) {
  int blk = blockIdx.x;
  int b = blk >> 3;
  int tt = (blk >> 1) & 3;
  int eh = blk & 1;
  int t0 = tt * 64, e0 = eh * 256;
  int tid = threadIdx.x;
  int wv = tid >> 6, ln = tid & 15, q = (tid >> 4) & 3;
  int t = t0 + wv * 16 + ln;
  const unsigned short* xrow = xe2bf + ((size_t)b * 256 + t) * 128 + q * 8;
  short8 bfrag[4];
#pragma unroll
  for (int kc = 0; kc < 4; ++kc) bfrag[kc] = *(const short8*)(xrow + kc * 32);
  float4v acc[16];
#pragma unroll
  for (int et = 0; et < 16; ++et) acc[et] = (float4v){0.f, 0.f, 0.f, 0.f};
#pragma unroll
  for (int et = 0; et < 16; ++et) {
    const unsigned short* arow = inwbf + (size_t)(e0 + et * 16 + ln) * 128 + q * 8;
#pragma unroll
    for (int kc = 0; kc < 4; ++kc) {
      short8 af = *(const short8*)(arow + kc * 32);
      acc[et] = __builtin_amdgcn_mfma_f32_16x16x32_bf16(af, bfrag[kc], acc[et], 0, 0, 0);
    }
  }
  unsigned short* orow = xz + ((size_t)b * 256 + t) * 512 + e0 + q * 4;
#pragma unroll
  for (int et = 0; et < 16; ++et) {
    short4v st = {(short)f2b(acc[et][0]), (short)f2b(acc[et][1]),
                  (short)f2b(acc[et][2]), (short)f2b(acc[et][3])};
    *(short4v*)(orow + et * 16) = st;
  }
}

// ---------------- mamba: causal depthwise conv (K=4) + SiLU, bf16 in/out ----------------
__global__ __launch_bounds__(256) void k_convsilu(const unsigned short* __restrict__ xz,
                                                  const float* __restrict__ cw,
                                                  const float* __restrict__ cb,
                                                  unsigned short* __restrict__ xc) {
  int i = blockIdx.x * 256 + threadIdx.x;
  int c2 = (i & 127) * 2;
  int t = (i >> 7) & 255;
  int b = i >> 15;
  const unsigned short* zb = xz + (size_t)b * 131072 + c2;
  float4 w0 = *(const float4*)&cw[c2 * 4];
  float4 w1 = *(const float4*)&cw[(c2 + 1) * 4];
  float wa[4] = {w0.x, w0.y, w0.z, w0.w};
  float wb[4] = {w1.x, w1.y, w1.z, w1.w};
  float acc0 = cb[c2], acc1 = cb[c2 + 1];
#pragma unroll
  for (int k = 0; k < 4; ++k) {
    int tt = t - 3 + k;
    if (tt >= 0) {
      ushort2 u2 = *(const ushort2*)&zb[(size_t)tt * 512];
      acc0 += b2f(u2.x) * wa[k];
      acc1 += b2f(u2.y) * wb[k];
    }
  }
  float r0 = acc0 / (1.0f + __expf(-acc0));
  float r1 = acc1 / (1.0f + __expf(-acc1));
  ushort2 o = {f2b(r0), f2b(r1)};
  *(ushort2*)&xc[(size_t)b * 65536 + (size_t)t * 256 + c2] = o;
}

// ---------------- mamba: x-projection via MFMA (48x256 padded weights), zero-LDS ----------------
__global__ __launch_bounds__(256) void k_xproj(const unsigned short* __restrict__ xc,
                                               const unsigned short* __restrict__ xwbf,
                                               float* __restrict__ dbl) {
  int blk = blockIdx.x;       // 256 = 64 b x 4 t-quads
  int b = blk >> 2;
  int tq = blk & 3;
  int tid = threadIdx.x;
  int wv = tid >> 6, ln = tid & 15, q = (tid >> 4) & 3;
  int t = tq * 64 + wv * 16 + ln;
  const unsigned short* xrow = xc + ((size_t)b * 256 + t) * 256 + q * 8;
  short8 bfrag[8];
#pragma unroll
  for (int kc = 0; kc < 8; ++kc) bfrag[kc] = *(const short8*)(xrow + kc * 32);
  float4v acc[3];
#pragma unroll
  for (int et = 0; et < 3; ++et) acc[et] = (float4v){0.f, 0.f, 0.f, 0.f};
#pragma unroll
  for (int et = 0; et < 3; ++et) {
    const unsigned short* arow = xwbf + (size_t)(et * 16 + ln) * 256 + q * 8;
#pragma unroll
    for (int kc = 0; kc < 8; ++kc) {
      short8 af = *(const short8*)(arow + kc * 32);
      acc[et] = __builtin_amdgcn_mfma_f32_16x16x32_bf16(af, bfrag[kc], acc[et], 0, 0, 0);
    }
  }
  float* drow = dbl + ((size_t)b * 256 + t) * 40;
#pragma unroll
  for (int et = 0; et < 3; ++et)
#pragma unroll
    for (int r = 0; r < 4; ++r) {
      int k = et * 16 + q * 4 + r;
      if (k < 40) drow[k] = acc[et][r];
    }
}

// ---------------- mamba: fused dt + selective scan + y-finalize (bf16 xc/z/y) ----------------
__global__ __launch_bounds__(128) void k_scan2(const float* __restrict__ dbl,
                                               const unsigned short* __restrict__ xc,
                                               const unsigned short* __restrict__ xz,
                                               const float* __restrict__ Alog,
                                               const float* __restrict__ dtw, const float* __restrict__ dtbv,
                                               const float* __restrict__ Dp, unsigned short* __restrict__ y) {
  __shared__ float ds[32][40];
  __shared__ float dxs[32][32][4];
  __shared__ float yl[32][32];
  __shared__ float dtwL[32][8];
  __shared__ float dtbL[32];
  __shared__ float DpL[32];

  int b = blockIdx.x >> 3;
  int c0 = (blockIdx.x & 7) * 32;
  int tid = threadIdx.x;

  for (int idx = tid; idx < 256; idx += 128) dtwL[idx >> 3][idx & 7] = dtw[(c0 + (idx >> 3)) * 8 + (idx & 7)];
  if (tid < 32) { dtbL[tid] = dtbv[c0 + tid]; DpL[tid] = Dp[c0 + tid]; }

  int lane = tid & 63;
  int wv = tid >> 6;
  int c_loc = wv * 16 + (lane >> 2);
  int c = c0 + c_loc;
  int sblk = (lane & 3) * 4;

  float4 Al = *(const float4*)&Alog[c * 16 + sblk];
  float A[4] = {-__expf(Al.x), -__expf(Al.y), -__expf(Al.z), -__expf(Al.w)};
  float h[4] = {0.f, 0.f, 0.f, 0.f};

  const float* dbp = dbl + (size_t)b * 10240;
  const unsigned short* xcp = xc + (size_t)b * 65536;
  const unsigned short* xzp = xz + (size_t)b * 131072;
  unsigned short* yp = y + (size_t)b * 65536;

  for (int chk = 0; chk < 8; ++chk) {
    int t0c = chk * 32;
    for (int idx = tid; idx < 1280; idx += 128) ((float*)ds)[idx] = dbp[t0c * 40 + idx];
    for (int idx = tid; idx < 512; idx += 128) {
      int t = idx >> 4, cc2 = (idx & 15) * 2;
      ushort2 xv = *(const ushort2*)&xcp[(size_t)(t0c + t) * 256 + c0 + cc2];
      ushort2 zv = *(const ushort2*)&xzp[(size_t)(t0c + t) * 512 + 256 + c0 + cc2];
      dxs[t][cc2][1] = b2f(xv.x);
      dxs[t][cc2 + 1][1] = b2f(xv.y);
      dxs[t][cc2][2] = b2f(zv.x);
      dxs[t][cc2 + 1][2] = b2f(zv.y);
    }
    __syncthreads();
    for (int idx = tid; idx < 1024; idx += 128) {
      int t = idx >> 5, cc = idx & 31;
      const float* dr = ds[t];
      const float* wr = dtwL[cc];
      float acc = dtbL[cc];
#pragma unroll
      for (int j = 0; j < 8; ++j) acc += wr[j] * dr[j];
      dxs[t][cc][0] = (acc > 20.0f) ? acc : __logf(1.0f + __expf(acc));
    }
    __syncthreads();
#pragma unroll 4
    for (int t = 0; t < 32; ++t) {
      float4 dx = *(const float4*)&dxs[t][c_loc][0];
      float4 Bv = *(const float4*)&ds[t][8 + sblk];
      float4 Cv = *(const float4*)&ds[t][24 + sblk];
      float dtv = dx.x;
      float bx = dtv * dx.y;
      h[0] = __expf(dtv * A[0]) * h[0] + Bv.x * bx;
      h[1] = __expf(dtv * A[1]) * h[1] + Bv.y * bx;
      h[2] = __expf(dtv * A[2]) * h[2] + Bv.z * bx;
      h[3] = __expf(dtv * A[3]) * h[3] + Bv.w * bx;
      float p = h[0] * Cv.x;
      p = fmaf(h[1], Cv.y, p);
      p = fmaf(h[2], Cv.z, p);
      p = fmaf(h[3], Cv.w, p);
      p += qxor1(p);
      p += qxor2(p);
      if ((lane & 3) == 0) yl[t][c_loc] = p;
    }
    __syncthreads();
    for (int idx = tid; idx < 512; idx += 128) {
      int t = idx >> 4, cc2 = (idx & 15) * 2;
      float p0 = yl[t][cc2], p1 = yl[t][cc2 + 1];
      float x0 = dxs[t][cc2][1], x1 = dxs[t][cc2 + 1][1];
      float z0 = dxs[t][cc2][2], z1 = dxs[t][cc2 + 1][2];
      float s0 = z0 / (1.0f + __expf(-z0));
      float s1 = z1 / (1.0f + __expf(-z1));
      ushort2 o = {f2b((p0 + DpL[cc2] * x0) * s0), f2b((p1 + DpL[cc2 + 1] * x1) * s1)};
      *(ushort2*)&yp[(size_t)(t0c + t) * 256 + c0 + cc2] = o;
    }
    __syncthreads();
  }
}

// ---------------- mamba: MFMA out-projection + residual + LayerNorm, zero-LDS ----------------
__global__ __launch_bounds__(128) void k_outln(const unsigned short* __restrict__ yb,
                                               const unsigned short* __restrict__ owbf,
                                               float* __restrict__ xe2, unsigned short* __restrict__ xe2bf,
                                               const float* __restrict__ g, const float* __restrict__ bb) {
  int blk = blockIdx.x;
  int b = blk >> 3;
  int t0 = (blk & 7) * 32;
  int tid = threadIdx.x;
  int wv = tid >> 6, ln = tid & 15, q = (tid >> 4) & 3;
  int t = t0 + wv * 16 + ln;

  const unsigned short* yrow = yb + ((size_t)b * 256 + t) * 256 + q * 8;
  short8 bfrag[8];
#pragma unroll
  for (int kc = 0; kc < 8; ++kc) bfrag[kc] = *(const short8*)(yrow + kc * 32);

  float4v acc[8];
#pragma unroll
  for (int et = 0; et < 8; ++et) acc[et] = (float4v){0.f, 0.f, 0.f, 0.f};
#pragma unroll
  for (int et = 0; et < 8; ++et) {
    const unsigned short* arow = owbf + (size_t)(et * 16 + ln) * 256 + q * 8;
#pragma unroll
    for (int kc = 0; kc < 8; ++kc) {
      short8 af = *(const short8*)(arow + kc * 32);
      acc[et] = __builtin_amdgcn_mfma_f32_16x16x32_bf16(af, bfrag[kc], acc[et], 0, 0, 0);
    }
  }

  float* xrow = xe2 + ((size_t)b * 256 + t) * 128;
  float vals[8][4];
  float s1 = 0.f, s2 = 0.f;
#pragma unroll
  for (int et = 0; et < 8; ++et) {
    float4 res = *(const float4*)(xrow + et * 16 + q * 4);
    float rv[4] = {res.x, res.y, res.z, res.w};
#pragma unroll
    for (int r = 0; r < 4; ++r) {
      float v = acc[et][r] + rv[r];
      vals[et][r] = v;
      s1 += v;
      s2 += v * v;
    }
  }
  s1 += __shfl_xor(s1, 16, 64);
  s1 += __shfl_xor(s1, 32, 64);
  s2 += __shfl_xor(s2, 16, 64);
  s2 += __shfl_xor(s2, 32, 64);
  float mu = s1 * (1.0f / 128.0f);
  float rs = rsqrtf(s2 * (1.0f / 128.0f) - mu * mu + 1e-5f);

  unsigned short* brow = xe2bf + ((size_t)b * 256 + t) * 128;
#pragma unroll
  for (int et = 0; et < 8; ++et) {
    int d = et * 16 + q * 4;
    float4 g4 = *(const float4*)(g + d);
    float4 b4 = *(const float4*)(bb + d);
    float o0 = (vals[et][0] - mu) * rs * g4.x + b4.x;
    float o1 = (vals[et][1] - mu) * rs * g4.y + b4.y;
    float o2 = (vals[et][2] - mu) * rs * g4.z + b4.z;
    float o3 = (vals[et][3] - mu) * rs * g4.w + b4.w;
    float4 of = {o0, o1, o2, o3};
    *(float4*)(xrow + d) = of;
    short4v ob = {(short)f2b(o0), (short)f2b(o1), (short)f2b(o2), (short)f2b(o3)};
    *(short4v*)(brow + d) = ob;
  }
}

// ---------------- xflat transpose ----------------
__global__ __launch_bounds__(256) void k_xflat(const float* __restrict__ xe2, float* __restrict__ out) {
  int b = blockIdx.x >> 5;
  int blk = blockIdx.x & 31;
  int t0 = (blk >> 2) * 32, d0 = (blk & 3) * 32;
  __shared__ float tile[32][33];
  int tid = threadIdx.x;
#pragma unroll
  for (int q = 0; q < 4; ++q) {
    int t = (tid >> 5) + q * 8, dd = tid & 31;
    tile[t][dd] = xe2[(size_t)b * 32768 + (size_t)(t0 + t) * 128 + d0 + dd];
  }
  __syncthreads();
#pragma unroll
  for (int q = 0; q < 4; ++q) {
    int dd = (tid >> 5) + q * 8, t = tid & 31;
    out[(size_t)b * 32768 + (size_t)(d0 + dd) * 256 + t0 + t] = tile[t][dd];
  }
}

// ---------------- final FC ----------------
__global__ __launch_bounds__(256) void k_fc(const float* __restrict__ xflat, const float* __restrict__ fw,
                                            const float* __restrict__ fb, float* __restrict__ pred) {
  int b = blockIdx.x;
  int tid = threadIdx.x;
  float acc[18];
#pragma unroll
  for (int c = 0; c < 18; ++c) acc[c] = 0.0f;
  const float* xb = xflat + (size_t)b * 32768;
  for (int i = tid * 4; i < 32768; i += 1024) {
    float4 xv = *(const float4*)&xb[i];
#pragma unroll
    for (int c = 0; c < 18; ++c) {
      float4 wv = *(const float4*)&fw[(size_t)c * 32768 + i];
      acc[c] += xv.x * wv.x + xv.y * wv.y + xv.z * wv.z + xv.w * wv.w;
    }
  }
  __shared__ float red[256];
  for (int c = 0; c < 18; ++c) {
    red[tid] = acc[c];
    __syncthreads();
    for (int off = 128; off > 0; off >>= 1) {
      if (tid < off) red[tid] += red[tid + off];
      __syncthreads();
    }
    if (tid == 0) pred[b * 18 + c] = red[0] + fb[c];
    __syncthreads();
  }
}

extern "C" void kernel_launch(void* const* d_in, const int* in_sizes, int n_in,
                              void* d_out, int out_size, void* d_ws, size_t ws_size,
                              hipStream_t stream) {
  (void)in_sizes; (void)n_in; (void)out_size; (void)ws_size;
  const float* inp    = (const float*)d_in[0];
  const float* emb_w  = (const float*)d_in[1];
  const float* emb_b  = (const float*)d_in[2];
  const float* dw_w   = (const float*)d_in[3];
  const float* dw_b   = (const float*)d_in[4];
  const float* pw_w   = (const float*)d_in[5];
  const float* pw_b   = (const float*)d_in[6];
  const float* se_w1  = (const float*)d_in[7];
  const float* se_b1  = (const float*)d_in[8];
  const float* se_w2  = (const float*)d_in[9];
  const float* se_b2  = (const float*)d_in[10];
  const float* in_w   = (const float*)d_in[11];
  const float* conv_w = (const float*)d_in[12];
  const float* conv_b = (const float*)d_in[13];
  const float* xp_w   = (const float*)d_in[14];
  const float* dt_w   = (const float*)d_in[15];
  const float* dt_b   = (const float*)d_in[16];
  const float* Alog   = (const float*)d_in[17];
  const float* Dp     = (const float*)d_in[18];
  const float* out_w  = (const float*)d_in[19];
  const float* ln_g   = (const float*)d_in[20];
  const float* ln_b   = (const float*)d_in[21];
  const float* fc_w   = (const float*)d_in[22];
  const float* fc_b   = (const float*)d_in[23];

  char* ws = (char*)d_ws;
  unsigned short* U0 = (unsigned short*)(ws);
  unsigned short* W0 = (unsigned short*)(ws + 50331648);
  unsigned short* U1 = (unsigned short*)(ws + 100663296);
  unsigned short* W1 = (unsigned short*)(ws + 150994944);
  float* abuf = (float*)(ws + 201326592);
  unsigned short* xz = (unsigned short*)(ws);               // bf16 (U0 region)
  unsigned short* xc = (unsigned short*)(ws + 33554432);    // bf16
  unsigned short* yb = (unsigned short*)(ws + 50331648);    // bf16 (W0 region)
  float* xe2 = (float*)(ws + 100663296);                    // fp32 (U1 region)
  float* dbl = (float*)(ws + 150994944);                    // fp32 (W1 region)
  unsigned short* xe2bf = (unsigned short*)(ws + 153616384);// bf16, 4 MB (W1 region tail)

  float* xflat = (float*)d_out;
  float* pred  = xflat + (size_t)64 * 32768;
  // bf16 weights in d_out scratch (overwritten by k_xflat at the end)
  unsigned short* pwbf  = (unsigned short*)d_out;           // 49152
  unsigned short* inwbf = pwbf + 49152;                     // 131072
  unsigned short* owbf  = inwbf + 131072;                   // 65536
  unsigned short* xwbf  = owbf + 65536;                     // 2 x 12288 (48x256 padded)
  unsigned short* ewbf  = xwbf + 24576;                     // 4096 (128x32 padded)

  k_cvt<<<1072, 256, 0, stream>>>(pw_w, in_w, out_w, xp_w, emb_w, pwbf);
  k_emb<<<768, 256, 0, stream>>>(inp, ewbf, emb_b, U0);

  k_blk<0><<<3072, 256, 0, stream>>>(U0, U0, abuf, dw_w, dw_b, pwbf, pw_b, U0, W0);
  k_se<<<768, 256, 0, stream>>>(W0, se_w1, se_b1, se_w2, se_b2, abuf);
  k_blk<1><<<3072, 256, 0, stream>>>(U0, W0, abuf, dw_w + 640, dw_b + 128, pwbf + 16384, pw_b + 128,
                                     U1, W1);
  k_se<<<768, 256, 0, stream>>>(W1, se_w1 + 4096, se_b1 + 32, se_w2 + 4096, se_b2 + 128, abuf);
  k_blk<1><<<3072, 256, 0, stream>>>(U1, W1, abuf, dw_w + 1280, dw_b + 256, pwbf + 32768, pw_b + 256,
                                     U0, W0);
  k_se<<<768, 256, 0, stream>>>(W0, se_w1 + 8192, se_b1 + 64, se_w2 + 8192, se_b2 + 256, abuf);

  k_reduce2<<<1024, 256, 0, stream>>>(U0, W0, abuf, xe2, xe2bf);

  for (int i = 0; i < 2; ++i) {
    k_inproj<<<512, 256, 0, stream>>>(xe2bf, inwbf + i * 65536, xz);
    k_convsilu<<<8192, 256, 0, stream>>>(xz, conv_w + i * 1024, conv_b + i * 256, xc);
    k_xproj<<<256, 256, 0, stream>>>(xc, xwbf + i * 12288, dbl);
    k_scan2<<<512, 128, 0, stream>>>(dbl, xc, xz, Alog + i * 4096,
                                     dt_w + i * 2048, dt_b + i * 256, Dp + i * 256, yb);
    k_outln<<<512, 128, 0, stream>>>(yb, owbf + i * 32768, xe2, xe2bf,
                                     ln_g + i * 128, ln_b + i * 128);
  }

  k_xflat<<<2048, 256, 0, stream>>>(xe2, xflat);
  k_fc<<<64, 256, 0, stream>>>(xflat, fc_w, fc_b, pred);
}

// Round 12
// 756.138 us; speedup vs baseline: 1.0378x; 1.0378x over previous
//
#include <hip/hip_runtime.h>
#include <math.h>

#define LL 2048
#define MM 12
#define DD 128
#define TP 256   // T

typedef short short8 __attribute__((ext_vector_type(8)));
typedef short short4v __attribute__((ext_vector_type(4)));
typedef float float4v __attribute__((ext_vector_type(4)));

static __device__ __forceinline__ unsigned short f2b(float f) {
  union { float f; unsigned int u; } x; x.f = f;
  unsigned int r = x.u + 0x7fffu + ((x.u >> 16) & 1u);
  return (unsigned short)(r >> 16);
}
static __device__ __forceinline__ float b2f(unsigned short u) {
  union { unsigned int u; float f; } x; x.u = ((unsigned int)u) << 16;
  return x.f;
}
static __device__ __forceinline__ float qxor1(float x) {
  int r = __builtin_amdgcn_mov_dpp(__builtin_bit_cast(int, x), 0xB1, 0xF, 0xF, true);
  return __builtin_bit_cast(float, r);
}
static __device__ __forceinline__ float qxor2(float x) {
  int r = __builtin_amdgcn_mov_dpp(__builtin_bit_cast(int, x), 0x4E, 0xF, 0xF, true);
  return __builtin_bit_cast(float, r);
}

// ---------------- convert all fp32 weights to bf16 (pw, in_w, out_w, padded xp_w, padded ew) ----------------
__global__ __launch_bounds__(256) void k_cvt(const float* __restrict__ pw_w, const float* __restrict__ in_w,
                                             const float* __restrict__ out_w, const float* __restrict__ xp_w,
                                             const float* __restrict__ ew,
                                             unsigned short* __restrict__ pwbf) {
  int i = blockIdx.x * 256 + threadIdx.x;
  if (i < 49152) { pwbf[i] = f2b(pw_w[i]); return; }
  int i2 = i - 49152;
  if (i2 < 131072) { pwbf[i] = f2b(in_w[i2]); return; }
  int i3 = i2 - 131072;
  if (i3 < 65536) { pwbf[i] = f2b(out_w[i3]); return; }
  int i4 = i3 - 65536;
  if (i4 < 24576) {
    int layer = (i4 < 12288) ? 0 : 1;
    int rem = i4 - layer * 12288;
    int k = rem >> 8, c = rem & 255;
    float v = (k < 40) ? xp_w[layer * 10240 + k * 256 + c] : 0.0f;
    pwbf[i] = f2b(v);
    return;
  }
  int i5 = i4 - 24576;
  if (i5 < 4096) {   // ew padded [128][32], zeros for k>=16
    int d = i5 >> 5, k = i5 & 31;
    float v = (k < 16) ? ew[d * 16 + k] : 0.0f;
    pwbf[i] = f2b(v);
  }
}

// ---------------- embedding via MFMA: strided conv1d = 128x256x16 GEMM per sig ----------------
__global__ __launch_bounds__(256) void k_emb(const float* __restrict__ inp,
                                             const unsigned short* __restrict__ ewbf,  // [128][32] bf16
                                             const float* __restrict__ eb,
                                             unsigned short* __restrict__ xe) {
  int sig = blockIdx.x;
  int b = sig / MM, m = sig % MM;
  __shared__ float xs[LL];
  const float* ib = inp + (size_t)b * LL * MM + m;
  int tid = threadIdx.x;
  for (int i = tid; i < LL; i += 256) xs[i] = ib[(size_t)i * MM];
  __syncthreads();
  int wv = tid >> 6, ln = tid & 15, q = (tid >> 4) & 3;
  short8 af[8];
#pragma unroll
  for (int et = 0; et < 8; ++et)
    af[et] = *(const short8*)(ewbf + (et * 16 + ln) * 32 + q * 8);
#pragma unroll
  for (int pass = 0; pass < 4; ++pass) {
    int t = pass * 64 + wv * 16 + ln;
    int l0 = t * 8 - 4;
    short8 bfrag;
#pragma unroll
    for (int j = 0; j < 8; ++j) {
      int k = q * 8 + j;
      int l = l0 + k;
      float v = (k < 16 && l >= 0 && l < LL) ? xs[l] : 0.0f;
      bfrag[j] = (short)f2b(v);
    }
    float4v acc[8];
#pragma unroll
    for (int et = 0; et < 8; ++et) {
      acc[et] = (float4v){0.f, 0.f, 0.f, 0.f};
      acc[et] = __builtin_amdgcn_mfma_f32_16x16x32_bf16(af[et], bfrag, acc[et], 0, 0, 0);
    }
    unsigned short* orow = xe + (size_t)sig * 32768 + (size_t)t * 128;
#pragma unroll
    for (int et = 0; et < 8; ++et) {
      int e = et * 16 + q * 4;
      float4 pb = *(const float4*)&eb[e];
      short4v st = {(short)f2b(acc[et][0] + pb.x), (short)f2b(acc[et][1] + pb.y),
                    (short)f2b(acc[et][2] + pb.z), (short)f2b(acc[et][3] + pb.w)};
      *(short4v*)(orow + e) = st;
    }
  }
}

// ---------------- fused block, [sig][t][d]; single-LDS two-phase v overlay + partial-sum epilogue ----------------
template<int UPD>
__global__ __launch_bounds__(256) void k_blk(const unsigned short* __restrict__ uin,
                                             const unsigned short* __restrict__ win,
                                             const float* __restrict__ abuf,
                                             const float* __restrict__ dww, const float* __restrict__ dwb,
                                             const unsigned short* __restrict__ pwbf,
                                             const float* __restrict__ pwb,
                                             unsigned short* __restrict__ uout,
                                             unsigned short* __restrict__ wout,
                                             float* __restrict__ sbuf) {
  __shared__ unsigned short us[68 * 136];
  __shared__ float sred[512];

  int sig = blockIdx.x >> 2;
  int t0 = (blockIdx.x & 3) * 64;
  int tid = threadIdx.x;
  const size_t gbase = (size_t)sig * 32768;
  int c8 = (tid & 15) * 8;

  float aloc[8];
  if (UPD) {
    float4 a0 = *(const float4*)&abuf[sig * 128 + c8];
    float4 a1 = *(const float4*)&abuf[sig * 128 + c8 + 4];
    aloc[0] = a0.x; aloc[1] = a0.y; aloc[2] = a0.z; aloc[3] = a0.w;
    aloc[4] = a1.x; aloc[5] = a1.y; aloc[6] = a1.z; aloc[7] = a1.w;
  }

  const short8 ZV = {0, 0, 0, 0, 0, 0, 0, 0};
#pragma unroll
  for (int it = 0; it < 5; ++it) {
    int idx = it * 256 + tid;
    if (idx < 1088) {
      int row = idx >> 4;
      int t = t0 - 2 + row;
      short8 u8 = ZV;
      if (t >= 0 && t < TP) {
        u8 = *(const short8*)(uin + gbase + (size_t)t * 128 + c8);
        if (UPD) {
          short8 w8 = *(const short8*)(win + gbase + (size_t)t * 128 + c8);
          short8 r;
#pragma unroll
          for (int j = 0; j < 8; ++j)
            r[j] = (short)f2b(b2f((unsigned short)u8[j]) + b2f((unsigned short)w8[j]) * aloc[j]);
          u8 = r;
          if (row >= 2 && row < 66)
            *(short8*)(uout + gbase + (size_t)(t0 + row - 2) * 128 + c8) = u8;
        }
      }
      *(short8*)(us + row * 136 + c8) = u8;
    }
  }
  __syncthreads();

  float wl[5][8], bl[8];
#pragma unroll
  for (int j = 0; j < 8; ++j) {
    bl[j] = dwb[c8 + j];
#pragma unroll
    for (int k = 0; k < 5; ++k) wl[k][j] = dww[(c8 + j) * 5 + k];
  }

  int r0 = tid >> 4;
  short8 vv[2];
#pragma unroll
  for (int s = 0; s < 2; ++s) {
    int i = r0 + s * 16;
    float acc[8];
#pragma unroll
    for (int j = 0; j < 8; ++j) acc[j] = bl[j];
#pragma unroll
    for (int k = 0; k < 5; ++k) {
      short8 u8 = *(const short8*)(us + (i + k) * 136 + c8);
#pragma unroll
      for (int j = 0; j < 8; ++j) acc[j] += b2f((unsigned short)u8[j]) * wl[k][j];
    }
#pragma unroll
    for (int j = 0; j < 8; ++j)
      vv[s][j] = (short)f2b(0.5f * acc[j] * (1.0f + erff(acc[j] * 0.70710678118654752f)));
  }
  __syncthreads();
#pragma unroll
  for (int s = 0; s < 2; ++s)
    *(short8*)(us + (r0 + s * 16) * 136 + c8) = vv[s];

#pragma unroll
  for (int s = 0; s < 2; ++s) {
    int i = 32 + r0 + s * 16;
    float acc[8];
#pragma unroll
    for (int j = 0; j < 8; ++j) acc[j] = bl[j];
#pragma unroll
    for (int k = 0; k < 5; ++k) {
      short8 u8 = *(const short8*)(us + (i + k) * 136 + c8);
#pragma unroll
      for (int j = 0; j < 8; ++j) acc[j] += b2f((unsigned short)u8[j]) * wl[k][j];
    }
#pragma unroll
    for (int j = 0; j < 8; ++j)
      vv[s][j] = (short)f2b(0.5f * acc[j] * (1.0f + erff(acc[j] * 0.70710678118654752f)));
  }
  __syncthreads();
#pragma unroll
  for (int s = 0; s < 2; ++s)
    *(short8*)(us + (32 + r0 + s * 16) * 136 + c8) = vv[s];
  __syncthreads();

  int wv = tid >> 6;
  int ln = tid & 15;
  int q  = (tid >> 4) & 3;
  int tw = wv * 16;
  float4v acc4[8];
#pragma unroll
  for (int et = 0; et < 8; ++et) acc4[et] = (float4v){0.f, 0.f, 0.f, 0.f};
#pragma unroll
  for (int kc = 0; kc < 4; ++kc) {
    int d0 = kc * 32;
    short8 bfrag = *(const short8*)(us + (tw + ln) * 136 + d0 + q * 8);
#pragma unroll
    for (int et = 0; et < 8; ++et) {
      short8 af = *(const short8*)(pwbf + (size_t)(et * 16 + ln) * 128 + d0 + q * 8);
      acc4[et] = __builtin_amdgcn_mfma_f32_16x16x32_bf16(af, bfrag, acc4[et], 0, 0, 0);
    }
  }

  int tg = t0 + tw + ln;
#pragma unroll
  for (int et = 0; et < 8; ++et) {
    int e = et * 16 + q * 4;
    float4 pb = *(const float4*)&pwb[e];
    float v0 = acc4[et][0] + pb.x;
    float v1 = acc4[et][1] + pb.y;
    float v2 = acc4[et][2] + pb.z;
    float v3 = acc4[et][3] + pb.w;
    short4v st = {(short)f2b(v0), (short)f2b(v1), (short)f2b(v2), (short)f2b(v3)};
    *(short4v*)(wout + gbase + (size_t)tg * 128 + e) = st;
    float s0 = v0, s1 = v1, s2 = v2, s3 = v3;
#pragma unroll
    for (int m = 1; m <= 8; m <<= 1) {
      s0 += __shfl_xor(s0, m, 64);
      s1 += __shfl_xor(s1, m, 64);
      s2 += __shfl_xor(s2, m, 64);
      s3 += __shfl_xor(s3, m, 64);
    }
    if (ln == 0) {
      float4 sv = {s0, s1, s2, s3};
      *(float4*)&sred[wv * 128 + e] = sv;
    }
  }
  __syncthreads();
  if (tid < 128) {
    float tot = sred[tid] + sred[128 + tid] + sred[256 + tid] + sred[384 + tid];
    sbuf[((size_t)sig * 4 + (blockIdx.x & 3)) * 128 + tid] = tot;
  }
}

// ---------------- SE gate (slim): 4-way partial add + two matvecs ----------------
__global__ __launch_bounds__(128) void k_se(const float* __restrict__ sbuf,
                                            const float* __restrict__ w1, const float* __restrict__ b1,
                                            const float* __restrict__ w2, const float* __restrict__ b2,
                                            float* __restrict__ abuf) {
  int sig = blockIdx.x;
  __shared__ float sm[128];
  __shared__ float hh[32];
  int tid = threadIdx.x;
  const float* sp = sbuf + (size_t)sig * 4 * 128;
  sm[tid] = (sp[tid] + sp[128 + tid] + sp[256 + tid] + sp[384 + tid]) * (1.0f / 256.0f);
  __syncthreads();
  if (tid < 32) {
    float acc = b1[tid];
    for (int d = 0; d < 128; ++d) acc += w1[tid * 128 + d] * sm[d];
    hh[tid] = fmaxf(acc, 0.0f);
  }
  __syncthreads();
  float acc = b2[tid];
#pragma unroll
  for (int r = 0; r < 32; ++r) acc += w2[tid * 32 + r] * hh[r];
  abuf[sig * 128 + tid] = 1.0f / (1.0f + expf(-acc));
}

// ---------------- final update + mean over M -> xe2 fp32 + xe2bf bf16 ----------------
__global__ __launch_bounds__(256) void k_reduce2(const unsigned short* __restrict__ u,
                                                 const unsigned short* __restrict__ w,
                                                 const float* __restrict__ abuf, float* __restrict__ xe2,
                                                 unsigned short* __restrict__ xe2bf) {
  int i = blockIdx.x * 256 + threadIdx.x;
  int d0 = (i & 15) * 8;
  int t = (i >> 4) & 255;
  int b = i >> 12;
  float acc[8] = {0.f, 0.f, 0.f, 0.f, 0.f, 0.f, 0.f, 0.f};
#pragma unroll 4
  for (int m = 0; m < 12; ++m) {
    size_t base = ((size_t)(b * 12 + m) * 256 + t) * 128 + d0;
    short8 u8 = *(const short8*)(u + base);
    short8 w8 = *(const short8*)(w + base);
    float4 a0 = *(const float4*)&abuf[(b * 12 + m) * 128 + d0];
    float4 a1 = *(const float4*)&abuf[(b * 12 + m) * 128 + d0 + 4];
    float av[8] = {a0.x, a0.y, a0.z, a0.w, a1.x, a1.y, a1.z, a1.w};
#pragma unroll
    for (int j = 0; j < 8; ++j)
      acc[j] += b2f((unsigned short)u8[j]) + b2f((unsigned short)w8[j]) * av[j];
  }
  size_t off = (size_t)b * 32768 + (size_t)t * 128 + d0;
  float4 o0 = {acc[0] / 12.f, acc[1] / 12.f, acc[2] / 12.f, acc[3] / 12.f};
  float4 o1 = {acc[4] / 12.f, acc[5] / 12.f, acc[6] / 12.f, acc[7] / 12.f};
  *(float4*)(xe2 + off) = o0;
  *(float4*)(xe2 + off + 4) = o1;
  short8 ob;
#pragma unroll
  for (int j = 0; j < 8; ++j) ob[j] = (short)f2b(acc[j] / 12.f);
  *(short8*)(xe2bf + off) = ob;
}

// ---------------- mamba: in-projection via MFMA, zero-LDS -> bf16 xz[t][e] ----------------
__global__ __launch_bounds__(256) void k_inproj(const unsigned short* __restrict__ xe2bf,
                                                const unsigned short* __restrict__ inwbf,
                                                unsigned short* __restrict__ xz) {
  int blk = blockIdx.x;
  int b = blk >> 3;
  int tt = (blk >> 1) & 3;
  int eh = blk & 1;
  int t0 = tt * 64, e0 = eh * 256;
  int tid = threadIdx.x;
  int wv = tid >> 6, ln = tid & 15, q = (tid >> 4) & 3;
  int t = t0 + wv * 16 + ln;
  const unsigned short* xrow = xe2bf + ((size_t)b * 256 + t) * 128 + q * 8;
  short8 bfrag[4];
#pragma unroll
  for (int kc = 0; kc < 4; ++kc) bfrag[kc] = *(const short8*)(xrow + kc * 32);
  float4v acc[16];
#pragma unroll
  for (int et = 0; et < 16; ++et) acc[et] = (float4v){0.f, 0.f, 0.f, 0.f};
#pragma unroll
  for (int et = 0; et < 16; ++et) {
    const unsigned short* arow = inwbf + (size_t)(e0 + et * 16 + ln) * 128 + q * 8;
#pragma unroll
    for (int kc = 0; kc < 4; ++kc) {
      short8 af = *(const short8*)(arow + kc * 32);
      acc[et] = __builtin_amdgcn_mfma_f32_16x16x32_bf16(af, bfrag[kc], acc[et], 0, 0, 0);
    }
  }
  unsigned short* orow = xz + ((size_t)b * 256 + t) * 512 + e0 + q * 4;
#pragma unroll
  for (int et = 0; et < 16; ++et) {
    short4v st = {(short)f2b(acc[et][0]), (short)f2b(acc[et][1]),
                  (short)f2b(acc[et][2]), (short)f2b(acc[et][3])};
    *(short4v*)(orow + et * 16) = st;
  }
}

// ---------------- mamba: causal depthwise conv (K=4) + SiLU, bf16 in/out ----------------
__global__ __launch_bounds__(256) void k_convsilu(const unsigned short* __restrict__ xz,
                                                  const float* __restrict__ cw,
                                                  const float* __restrict__ cb,
                                                  unsigned short* __restrict__ xc) {
  int i = blockIdx.x * 256 + threadIdx.x;
  int c2 = (i & 127) * 2;
  int t = (i >> 7) & 255;
  int b = i >> 15;
  const unsigned short* zb = xz + (size_t)b * 131072 + c2;
  float4 w0 = *(const float4*)&cw[c2 * 4];
  float4 w1 = *(const float4*)&cw[(c2 + 1) * 4];
  float wa[4] = {w0.x, w0.y, w0.z, w0.w};
  float wb[4] = {w1.x, w1.y, w1.z, w1.w};
  float acc0 = cb[c2], acc1 = cb[c2 + 1];
#pragma unroll
  for (int k = 0; k < 4; ++k) {
    int tt = t - 3 + k;
    if (tt >= 0) {
      ushort2 u2 = *(const ushort2*)&zb[(size_t)tt * 512];
      acc0 += b2f(u2.x) * wa[k];
      acc1 += b2f(u2.y) * wb[k];
    }
  }
  float r0 = acc0 / (1.0f + __expf(-acc0));
  float r1 = acc1 / (1.0f + __expf(-acc1));
  ushort2 o = {f2b(r0), f2b(r1)};
  *(ushort2*)&xc[(size_t)b * 65536 + (size_t)t * 256 + c2] = o;
}

// ---------------- mamba: x-projection via MFMA (48x256 padded weights), zero-LDS ----------------
__global__ __launch_bounds__(256) void k_xproj(const unsigned short* __restrict__ xc,
                                               const unsigned short* __restrict__ xwbf,
                                               float* __restrict__ dbl) {
  int blk = blockIdx.x;       // 256 = 64 b x 4 t-quads
  int b = blk >> 2;
  int tq = blk & 3;
  int tid = threadIdx.x;
  int wv = tid >> 6, ln = tid & 15, q = (tid >> 4) & 3;
  int t = tq * 64 + wv * 16 + ln;
  const unsigned short* xrow = xc + ((size_t)b * 256 + t) * 256 + q * 8;
  short8 bfrag[8];
#pragma unroll
  for (int kc = 0; kc < 8; ++kc) bfrag[kc] = *(const short8*)(xrow + kc * 32);
  float4v acc[3];
#pragma unroll
  for (int et = 0; et < 3; ++et) acc[et] = (float4v){0.f, 0.f, 0.f, 0.f};
#pragma unroll
  for (int et = 0; et < 3; ++et) {
    const unsigned short* arow = xwbf + (size_t)(et * 16 + ln) * 256 + q * 8;
#pragma unroll
    for (int kc = 0; kc < 8; ++kc) {
      short8 af = *(const short8*)(arow + kc * 32);
      acc[et] = __builtin_amdgcn_mfma_f32_16x16x32_bf16(af, bfrag[kc], acc[et], 0, 0, 0);
    }
  }
  float* drow = dbl + ((size_t)b * 256 + t) * 40;
#pragma unroll
  for (int et = 0; et < 3; ++et)
#pragma unroll
    for (int r = 0; r < 4; ++r) {
      int k = et * 16 + q * 4 + r;
      if (k < 40) drow[k] = acc[et][r];
    }
}

// ---------------- mamba: fused dt + selective scan + y-finalize (bf16 xc/z/y) ----------------
__global__ __launch_bounds__(128) void k_scan2(const float* __restrict__ dbl,
                                               const unsigned short* __restrict__ xc,
                                               const unsigned short* __restrict__ xz,
                                               const float* __restrict__ Alog,
                                               const float* __restrict__ dtw, const float* __restrict__ dtbv,
                                               const float* __restrict__ Dp, unsigned short* __restrict__ y) {
  __shared__ float ds[32][40];
  __shared__ float dxs[32][32][4];
  __shared__ float yl[32][32];
  __shared__ float dtwL[32][8];
  __shared__ float dtbL[32];
  __shared__ float DpL[32];

  int b = blockIdx.x >> 3;
  int c0 = (blockIdx.x & 7) * 32;
  int tid = threadIdx.x;

  for (int idx = tid; idx < 256; idx += 128) dtwL[idx >> 3][idx & 7] = dtw[(c0 + (idx >> 3)) * 8 + (idx & 7)];
  if (tid < 32) { dtbL[tid] = dtbv[c0 + tid]; DpL[tid] = Dp[c0 + tid]; }

  int lane = tid & 63;
  int wv = tid >> 6;
  int c_loc = wv * 16 + (lane >> 2);
  int c = c0 + c_loc;
  int sblk = (lane & 3) * 4;

  float4 Al = *(const float4*)&Alog[c * 16 + sblk];
  float A[4] = {-__expf(Al.x), -__expf(Al.y), -__expf(Al.z), -__expf(Al.w)};
  float h[4] = {0.f, 0.f, 0.f, 0.f};

  const float* dbp = dbl + (size_t)b * 10240;
  const unsigned short* xcp = xc + (size_t)b * 65536;
  const unsigned short* xzp = xz + (size_t)b * 131072;
  unsigned short* yp = y + (size_t)b * 65536;

  for (int chk = 0; chk < 8; ++chk) {
    int t0c = chk * 32;
    for (int idx = tid; idx < 1280; idx += 128) ((float*)ds)[idx] = dbp[t0c * 40 + idx];
    for (int idx = tid; idx < 512; idx += 128) {
      int t = idx >> 4, cc2 = (idx & 15) * 2;
      ushort2 xv = *(const ushort2*)&xcp[(size_t)(t0c + t) * 256 + c0 + cc2];
      ushort2 zv = *(const ushort2*)&xzp[(size_t)(t0c + t) * 512 + 256 + c0 + cc2];
      dxs[t][cc2][1] = b2f(xv.x);
      dxs[t][cc2 + 1][1] = b2f(xv.y);
      dxs[t][cc2][2] = b2f(zv.x);
      dxs[t][cc2 + 1][2] = b2f(zv.y);
    }
    __syncthreads();
    for (int idx = tid; idx < 1024; idx += 128) {
      int t = idx >> 5, cc = idx & 31;
      const float* dr = ds[t];
      const float* wr = dtwL[cc];
      float acc = dtbL[cc];
#pragma unroll
      for (int j = 0; j < 8; ++j) acc += wr[j] * dr[j];
      dxs[t][cc][0] = (acc > 20.0f) ? acc : __logf(1.0f + __expf(acc));
    }
    __syncthreads();
#pragma unroll 4
    for (int t = 0; t < 32; ++t) {
      float4 dx = *(const float4*)&dxs[t][c_loc][0];
      float4 Bv = *(const float4*)&ds[t][8 + sblk];
      float4 Cv = *(const float4*)&ds[t][24 + sblk];
      float dtv = dx.x;
      float bx = dtv * dx.y;
      h[0] = __expf(dtv * A[0]) * h[0] + Bv.x * bx;
      h[1] = __expf(dtv * A[1]) * h[1] + Bv.y * bx;
      h[2] = __expf(dtv * A[2]) * h[2] + Bv.z * bx;
      h[3] = __expf(dtv * A[3]) * h[3] + Bv.w * bx;
      float p = h[0] * Cv.x;
      p = fmaf(h[1], Cv.y, p);
      p = fmaf(h[2], Cv.z, p);
      p = fmaf(h[3], Cv.w, p);
      p += qxor1(p);
      p += qxor2(p);
      if ((lane & 3) == 0) yl[t][c_loc] = p;
    }
    __syncthreads();
    for (int idx = tid; idx < 512; idx += 128) {
      int t = idx >> 4, cc2 = (idx & 15) * 2;
      float p0 = yl[t][cc2], p1 = yl[t][cc2 + 1];
      float x0 = dxs[t][cc2][1], x1 = dxs[t][cc2 + 1][1];
      float z0 = dxs[t][cc2][2], z1 = dxs[t][cc2 + 1][2];
      float s0 = z0 / (1.0f + __expf(-z0));
      float s1 = z1 / (1.0f + __expf(-z1));
      ushort2 o = {f2b((p0 + DpL[cc2] * x0) * s0), f2b((p1 + DpL[cc2 + 1] * x1) * s1)};
      *(ushort2*)&yp[(size_t)(t0c + t) * 256 + c0 + cc2] = o;
    }
    __syncthreads();
  }
}

// ---------------- mamba: MFMA out-projection + residual + LayerNorm, zero-LDS ----------------
__global__ __launch_bounds__(128) void k_outln(const unsigned short* __restrict__ yb,
                                               const unsigned short* __restrict__ owbf,
                                               float* __restrict__ xe2, unsigned short* __restrict__ xe2bf,
                                               const float* __restrict__ g, const float* __restrict__ bb) {
  int blk = blockIdx.x;
  int b = blk >> 3;
  int t0 = (blk & 7) * 32;
  int tid = threadIdx.x;
  int wv = tid >> 6, ln = tid & 15, q = (tid >> 4) & 3;
  int t = t0 + wv * 16 + ln;

  const unsigned short* yrow = yb + ((size_t)b * 256 + t) * 256 + q * 8;
  short8 bfrag[8];
#pragma unroll
  for (int kc = 0; kc < 8; ++kc) bfrag[kc] = *(const short8*)(yrow + kc * 32);

  float4v acc[8];
#pragma unroll
  for (int et = 0; et < 8; ++et) acc[et] = (float4v){0.f, 0.f, 0.f, 0.f};
#pragma unroll
  for (int et = 0; et < 8; ++et) {
    const unsigned short* arow = owbf + (size_t)(et * 16 + ln) * 256 + q * 8;
#pragma unroll
    for (int kc = 0; kc < 8; ++kc) {
      short8 af = *(const short8*)(arow + kc * 32);
      acc[et] = __builtin_amdgcn_mfma_f32_16x16x32_bf16(af, bfrag[kc], acc[et], 0, 0, 0);
    }
  }

  float* xrow = xe2 + ((size_t)b * 256 + t) * 128;
  float vals[8][4];
  float s1 = 0.f, s2 = 0.f;
#pragma unroll
  for (int et = 0; et < 8; ++et) {
    float4 res = *(const float4*)(xrow + et * 16 + q * 4);
    float rv[4] = {res.x, res.y, res.z, res.w};
#pragma unroll
    for (int r = 0; r < 4; ++r) {
      float v = acc[et][r] + rv[r];
      vals[et][r] = v;
      s1 += v;
      s2 += v * v;
    }
  }
  s1 += __shfl_xor(s1, 16, 64);
  s1 += __shfl_xor(s1, 32, 64);
  s2 += __shfl_xor(s2, 16, 64);
  s2 += __shfl_xor(s2, 32, 64);
  float mu = s1 * (1.0f / 128.0f);
  float rs = rsqrtf(s2 * (1.0f / 128.0f) - mu * mu + 1e-5f);

  unsigned short* brow = xe2bf + ((size_t)b * 256 + t) * 128;
#pragma unroll
  for (int et = 0; et < 8; ++et) {
    int d = et * 16 + q * 4;
    float4 g4 = *(const float4*)(g + d);
    float4 b4 = *(const float4*)(bb + d);
    float o0 = (vals[et][0] - mu) * rs * g4.x + b4.x;
    float o1 = (vals[et][1] - mu) * rs * g4.y + b4.y;
    float o2 = (vals[et][2] - mu) * rs * g4.z + b4.z;
    float o3 = (vals[et][3] - mu) * rs * g4.w + b4.w;
    float4 of = {o0, o1, o2, o3};
    *(float4*)(xrow + d) = of;
    short4v ob = {(short)f2b(o0), (short)f2b(o1), (short)f2b(o2), (short)f2b(o3)};
    *(short4v*)(brow + d) = ob;
  }
}

// ---------------- xflat transpose ----------------
__global__ __launch_bounds__(256) void k_xflat(const float* __restrict__ xe2, float* __restrict__ out) {
  int b = blockIdx.x >> 5;
  int blk = blockIdx.x & 31;
  int t0 = (blk >> 2) * 32, d0 = (blk & 3) * 32;
  __shared__ float tile[32][33];
  int tid = threadIdx.x;
#pragma unroll
  for (int q = 0; q < 4; ++q) {
    int t = (tid >> 5) + q * 8, dd = tid & 31;
    tile[t][dd] = xe2[(size_t)b * 32768 + (size_t)(t0 + t) * 128 + d0 + dd];
  }
  __syncthreads();
#pragma unroll
  for (int q = 0; q < 4; ++q) {
    int dd = (tid >> 5) + q * 8, t = tid & 31;
    out[(size_t)b * 32768 + (size_t)(d0 + dd) * 256 + t0 + t] = tile[t][dd];
  }
}

// ---------------- final FC ----------------
__global__ __launch_bounds__(256) void k_fc(const float* __restrict__ xflat, const float* __restrict__ fw,
                                            const float* __restrict__ fb, float* __restrict__ pred) {
  int b = blockIdx.x;
  int tid = threadIdx.x;
  float acc[18];
#pragma unroll
  for (int c = 0; c < 18; ++c) acc[c] = 0.0f;
  const float* xb = xflat + (size_t)b * 32768;
  for (int i = tid * 4; i < 32768; i += 1024) {
    float4 xv = *(const float4*)&xb[i];
#pragma unroll
    for (int c = 0; c < 18; ++c) {
      float4 wv = *(const float4*)&fw[(size_t)c * 32768 + i];
      acc[c] += xv.x * wv.x + xv.y * wv.y + xv.z * wv.z + xv.w * wv.w;
    }
  }
  __shared__ float red[256];
  for (int c = 0; c < 18; ++c) {
    red[tid] = acc[c];
    __syncthreads();
    for (int off = 128; off > 0; off >>= 1) {
      if (tid < off) red[tid] += red[tid + off];
      __syncthreads();
    }
    if (tid == 0) pred[b * 18 + c] = red[0] + fb[c];
    __syncthreads();
  }
}

extern "C" void kernel_launch(void* const* d_in, const int* in_sizes, int n_in,
                              void* d_out, int out_size, void* d_ws, size_t ws_size,
                              hipStream_t stream) {
  (void)in_sizes; (void)n_in; (void)out_size; (void)ws_size;
  const float* inp    = (const float*)d_in[0];
  const float* emb_w  = (const float*)d_in[1];
  const float* emb_b  = (const float*)d_in[2];
  const float* dw_w   = (const float*)d_in[3];
  const float* dw_b   = (const float*)d_in[4];
  const float* pw_w   = (const float*)d_in[5];
  const float* pw_b   = (const float*)d_in[6];
  const float* se_w1  = (const float*)d_in[7];
  const float* se_b1  = (const float*)d_in[8];
  const float* se_w2  = (const float*)d_in[9];
  const float* se_b2  = (const float*)d_in[10];
  const float* in_w   = (const float*)d_in[11];
  const float* conv_w = (const float*)d_in[12];
  const float* conv_b = (const float*)d_in[13];
  const float* xp_w   = (const float*)d_in[14];
  const float* dt_w   = (const float*)d_in[15];
  const float* dt_b   = (const float*)d_in[16];
  const float* Alog   = (const float*)d_in[17];
  const float* Dp     = (const float*)d_in[18];
  const float* out_w  = (const float*)d_in[19];
  const float* ln_g   = (const float*)d_in[20];
  const float* ln_b   = (const float*)d_in[21];
  const float* fc_w   = (const float*)d_in[22];
  const float* fc_b   = (const float*)d_in[23];

  char* ws = (char*)d_ws;
  unsigned short* U0 = (unsigned short*)(ws);
  unsigned short* W0 = (unsigned short*)(ws + 50331648);
  unsigned short* U1 = (unsigned short*)(ws + 100663296);
  unsigned short* W1 = (unsigned short*)(ws + 150994944);
  float* abuf = (float*)(ws + 201326592);                   // 98304 floats
  float* sbuf = abuf + 98304;                               // 393216 floats (768*4*128)
  unsigned short* xz = (unsigned short*)(ws);               // bf16 (U0 region)
  unsigned short* xc = (unsigned short*)(ws + 33554432);    // bf16
  unsigned short* yb = (unsigned short*)(ws + 50331648);    // bf16 (W0 region)
  float* xe2 = (float*)(ws + 100663296);                    // fp32 (U1 region)
  float* dbl = (float*)(ws + 150994944);                    // fp32 (W1 region)
  unsigned short* xe2bf = (unsigned short*)(ws + 153616384);// bf16, 4 MB (W1 region tail)

  float* xflat = (float*)d_out;
  float* pred  = xflat + (size_t)64 * 32768;
  // bf16 weights in d_out scratch (overwritten by k_xflat at the end)
  unsigned short* pwbf  = (unsigned short*)d_out;           // 49152
  unsigned short* inwbf = pwbf + 49152;                     // 131072
  unsigned short* owbf  = inwbf + 131072;                   // 65536
  unsigned short* xwbf  = owbf + 65536;                     // 2 x 12288 (48x256 padded)
  unsigned short* ewbf  = xwbf + 24576;                     // 4096 (128x32 padded)

  k_cvt<<<1072, 256, 0, stream>>>(pw_w, in_w, out_w, xp_w, emb_w, pwbf);
  k_emb<<<768, 256, 0, stream>>>(inp, ewbf, emb_b, U0);

  k_blk<0><<<3072, 256, 0, stream>>>(U0, U0, abuf, dw_w, dw_b, pwbf, pw_b, U0, W0, sbuf);
  k_se<<<768, 128, 0, stream>>>(sbuf, se_w1, se_b1, se_w2, se_b2, abuf);
  k_blk<1><<<3072, 256, 0, stream>>>(U0, W0, abuf, dw_w + 640, dw_b + 128, pwbf + 16384, pw_b + 128,
                                     U1, W1, sbuf);
  k_se<<<768, 128, 0, stream>>>(sbuf, se_w1 + 4096, se_b1 + 32, se_w2 + 4096, se_b2 + 128, abuf);
  k_blk<1><<<3072, 256, 0, stream>>>(U1, W1, abuf, dw_w + 1280, dw_b + 256, pwbf + 32768, pw_b + 256,
                                     U0, W0, sbuf);
  k_se<<<768, 128, 0, stream>>>(sbuf, se_w1 + 8192, se_b1 + 64, se_w2 + 8192, se_b2 + 256, abuf);

  k_reduce2<<<1024, 256, 0, stream>>>(U0, W0, abuf, xe2, xe2bf);

  for (int i = 0; i < 2; ++i) {
    k_inproj<<<512, 256, 0, stream>>>(xe2bf, inwbf + i * 65536, xz);
    k_convsilu<<<8192, 256, 0, stream>>>(xz, conv_w + i * 1024, conv_b + i * 256, xc);
    k_xproj<<<256, 256, 0, stream>>>(xc, xwbf + i * 12288, dbl);
    k_scan2<<<512, 128, 0, stream>>>(dbl, xc, xz, Alog + i * 4096,
                                     dt_w + i * 2048, dt_b + i * 256, Dp + i * 256, yb);
    k_outln<<<512, 128, 0, stream>>>(yb, owbf + i * 32768, xe2, xe2bf,
                                     ln_g + i * 128, ln_b + i * 128);
  }

  k_xflat<<<2048, 256, 0, stream>>>(xe2, xflat);
  k_fc<<<64, 256, 0, stream>>>(xflat, fc_w, fc_b, pred);
}

// Round 13
// 723.998 us; speedup vs baseline: 1.0838x; 1.0444x over previous
//
#include <hip/hip_runtime.h>
#include <math.h>

#define LL 2048
#define MM 12
#define DD 128
#define TP 256   // T

typedef short short8 __attribute__((ext_vector_type(8)));
typedef short short4v __attribute__((ext_vector_type(4)));
typedef float float4v __attribute__((ext_vector_type(4)));

static __device__ __forceinline__ unsigned short f2b(float f) {
  union { float f; unsigned int u; } x; x.f = f;
  unsigned int r = x.u + 0x7fffu + ((x.u >> 16) & 1u);
  return (unsigned short)(r >> 16);
}
static __device__ __forceinline__ float b2f(unsigned short u) {
  union { unsigned int u; float f; } x; x.u = ((unsigned int)u) << 16;
  return x.f;
}
static __device__ __forceinline__ float qxor1(float x) {
  int r = __builtin_amdgcn_mov_dpp(__builtin_bit_cast(int, x), 0xB1, 0xF, 0xF, true);
  return __builtin_bit_cast(float, r);
}
static __device__ __forceinline__ float qxor2(float x) {
  int r = __builtin_amdgcn_mov_dpp(__builtin_bit_cast(int, x), 0x4E, 0xF, 0xF, true);
  return __builtin_bit_cast(float, r);
}

// ---------------- convert weights to bf16 (pw, in_w, out_w, padded xp_w, padded ew) ----------------
__global__ __launch_bounds__(256) void k_cvt(const float* __restrict__ pw_w, const float* __restrict__ in_w,
                                             const float* __restrict__ out_w, const float* __restrict__ xp_w,
                                             const float* __restrict__ ew,
                                             unsigned short* __restrict__ pwbf) {
  int i = blockIdx.x * 256 + threadIdx.x;
  if (i < 49152) { pwbf[i] = f2b(pw_w[i]); return; }
  int i2 = i - 49152;
  if (i2 < 131072) { pwbf[i] = f2b(in_w[i2]); return; }
  int i3 = i2 - 131072;
  if (i3 < 65536) { pwbf[i] = f2b(out_w[i3]); return; }
  int i4 = i3 - 65536;
  if (i4 < 24576) {
    int layer = (i4 < 12288) ? 0 : 1;
    int rem = i4 - layer * 12288;
    int k = rem >> 8, c = rem & 255;
    float v = (k < 40) ? xp_w[layer * 10240 + k * 256 + c] : 0.0f;
    pwbf[i] = f2b(v);
    return;
  }
  int i5 = i4 - 24576;
  if (i5 < 4096) {
    int d = i5 >> 5, k = i5 & 31;
    float v = (k < 16) ? ew[d * 16 + k] : 0.0f;
    pwbf[i] = f2b(v);
  }
}

// ---------------- convert fc_w -> bf16 padded [32][32768] (after block stage frees U1 tail) ----------------
__global__ __launch_bounds__(256) void k_cvt2(const float* __restrict__ fw, unsigned short* __restrict__ fwbf) {
  int i = blockIdx.x * 256 + threadIdx.x;   // 1048576
  int m = i >> 15, k = i & 32767;
  fwbf[i] = f2b((m < 18) ? fw[m * 32768 + k] : 0.0f);
}

// ---------------- embedding via MFMA ----------------
__global__ __launch_bounds__(256) void k_emb(const float* __restrict__ inp,
                                             const unsigned short* __restrict__ ewbf,
                                             const float* __restrict__ eb,
                                             unsigned short* __restrict__ xe) {
  int sig = blockIdx.x;
  int b = sig / MM, m = sig % MM;
  __shared__ float xs[LL];
  const float* ib = inp + (size_t)b * LL * MM + m;
  int tid = threadIdx.x;
  for (int i = tid; i < LL; i += 256) xs[i] = ib[(size_t)i * MM];
  __syncthreads();
  int wv = tid >> 6, ln = tid & 15, q = (tid >> 4) & 3;
  short8 af[8];
#pragma unroll
  for (int et = 0; et < 8; ++et)
    af[et] = *(const short8*)(ewbf + (et * 16 + ln) * 32 + q * 8);
#pragma unroll
  for (int pass = 0; pass < 4; ++pass) {
    int t = pass * 64 + wv * 16 + ln;
    int l0 = t * 8 - 4;
    short8 bfrag;
#pragma unroll
    for (int j = 0; j < 8; ++j) {
      int k = q * 8 + j;
      int l = l0 + k;
      float v = (k < 16 && l >= 0 && l < LL) ? xs[l] : 0.0f;
      bfrag[j] = (short)f2b(v);
    }
    float4v acc[8];
#pragma unroll
    for (int et = 0; et < 8; ++et) {
      acc[et] = (float4v){0.f, 0.f, 0.f, 0.f};
      acc[et] = __builtin_amdgcn_mfma_f32_16x16x32_bf16(af[et], bfrag, acc[et], 0, 0, 0);
    }
    unsigned short* orow = xe + (size_t)sig * 32768 + (size_t)t * 128;
#pragma unroll
    for (int et = 0; et < 8; ++et) {
      int e = et * 16 + q * 4;
      float4 pb = *(const float4*)&eb[e];
      short4v st = {(short)f2b(acc[et][0] + pb.x), (short)f2b(acc[et][1] + pb.y),
                    (short)f2b(acc[et][2] + pb.z), (short)f2b(acc[et][3] + pb.w)};
      *(short4v*)(orow + e) = st;
    }
  }
}

// ---------------- fused block (unchanged from R12) ----------------
template<int UPD>
__global__ __launch_bounds__(256) void k_blk(const unsigned short* __restrict__ uin,
                                             const unsigned short* __restrict__ win,
                                             const float* __restrict__ abuf,
                                             const float* __restrict__ dww, const float* __restrict__ dwb,
                                             const unsigned short* __restrict__ pwbf,
                                             const float* __restrict__ pwb,
                                             unsigned short* __restrict__ uout,
                                             unsigned short* __restrict__ wout,
                                             float* __restrict__ sbuf) {
  __shared__ unsigned short us[68 * 136];
  __shared__ float sred[512];

  int sig = blockIdx.x >> 2;
  int t0 = (blockIdx.x & 3) * 64;
  int tid = threadIdx.x;
  const size_t gbase = (size_t)sig * 32768;
  int c8 = (tid & 15) * 8;

  float aloc[8];
  if (UPD) {
    float4 a0 = *(const float4*)&abuf[sig * 128 + c8];
    float4 a1 = *(const float4*)&abuf[sig * 128 + c8 + 4];
    aloc[0] = a0.x; aloc[1] = a0.y; aloc[2] = a0.z; aloc[3] = a0.w;
    aloc[4] = a1.x; aloc[5] = a1.y; aloc[6] = a1.z; aloc[7] = a1.w;
  }

  const short8 ZV = {0, 0, 0, 0, 0, 0, 0, 0};
#pragma unroll
  for (int it = 0; it < 5; ++it) {
    int idx = it * 256 + tid;
    if (idx < 1088) {
      int row = idx >> 4;
      int t = t0 - 2 + row;
      short8 u8 = ZV;
      if (t >= 0 && t < TP) {
        u8 = *(const short8*)(uin + gbase + (size_t)t * 128 + c8);
        if (UPD) {
          short8 w8 = *(const short8*)(win + gbase + (size_t)t * 128 + c8);
          short8 r;
#pragma unroll
          for (int j = 0; j < 8; ++j)
            r[j] = (short)f2b(b2f((unsigned short)u8[j]) + b2f((unsigned short)w8[j]) * aloc[j]);
          u8 = r;
          if (row >= 2 && row < 66)
            *(short8*)(uout + gbase + (size_t)(t0 + row - 2) * 128 + c8) = u8;
        }
      }
      *(short8*)(us + row * 136 + c8) = u8;
    }
  }
  __syncthreads();

  float wl[5][8], bl[8];
#pragma unroll
  for (int j = 0; j < 8; ++j) {
    bl[j] = dwb[c8 + j];
#pragma unroll
    for (int k = 0; k < 5; ++k) wl[k][j] = dww[(c8 + j) * 5 + k];
  }

  int r0 = tid >> 4;
  short8 vv[2];
#pragma unroll
  for (int s = 0; s < 2; ++s) {
    int i = r0 + s * 16;
    float acc[8];
#pragma unroll
    for (int j = 0; j < 8; ++j) acc[j] = bl[j];
#pragma unroll
    for (int k = 0; k < 5; ++k) {
      short8 u8 = *(const short8*)(us + (i + k) * 136 + c8);
#pragma unroll
      for (int j = 0; j < 8; ++j) acc[j] += b2f((unsigned short)u8[j]) * wl[k][j];
    }
#pragma unroll
    for (int j = 0; j < 8; ++j)
      vv[s][j] = (short)f2b(0.5f * acc[j] * (1.0f + erff(acc[j] * 0.70710678118654752f)));
  }
  __syncthreads();
#pragma unroll
  for (int s = 0; s < 2; ++s)
    *(short8*)(us + (r0 + s * 16) * 136 + c8) = vv[s];

#pragma unroll
  for (int s = 0; s < 2; ++s) {
    int i = 32 + r0 + s * 16;
    float acc[8];
#pragma unroll
    for (int j = 0; j < 8; ++j) acc[j] = bl[j];
#pragma unroll
    for (int k = 0; k < 5; ++k) {
      short8 u8 = *(const short8*)(us + (i + k) * 136 + c8);
#pragma unroll
      for (int j = 0; j < 8; ++j) acc[j] += b2f((unsigned short)u8[j]) * wl[k][j];
    }
#pragma unroll
    for (int j = 0; j < 8; ++j)
      vv[s][j] = (short)f2b(0.5f * acc[j] * (1.0f + erff(acc[j] * 0.70710678118654752f)));
  }
  __syncthreads();
#pragma unroll
  for (int s = 0; s < 2; ++s)
    *(short8*)(us + (32 + r0 + s * 16) * 136 + c8) = vv[s];
  __syncthreads();

  int wv = tid >> 6;
  int ln = tid & 15;
  int q  = (tid >> 4) & 3;
  int tw = wv * 16;
  float4v acc4[8];
#pragma unroll
  for (int et = 0; et < 8; ++et) acc4[et] = (float4v){0.f, 0.f, 0.f, 0.f};
#pragma unroll
  for (int kc = 0; kc < 4; ++kc) {
    int d0 = kc * 32;
    short8 bfrag = *(const short8*)(us + (tw + ln) * 136 + d0 + q * 8);
#pragma unroll
    for (int et = 0; et < 8; ++et) {
      short8 af = *(const short8*)(pwbf + (size_t)(et * 16 + ln) * 128 + d0 + q * 8);
      acc4[et] = __builtin_amdgcn_mfma_f32_16x16x32_bf16(af, bfrag, acc4[et], 0, 0, 0);
    }
  }

  int tg = t0 + tw + ln;
#pragma unroll
  for (int et = 0; et < 8; ++et) {
    int e = et * 16 + q * 4;
    float4 pb = *(const float4*)&pwb[e];
    float v0 = acc4[et][0] + pb.x;
    float v1 = acc4[et][1] + pb.y;
    float v2 = acc4[et][2] + pb.z;
    float v3 = acc4[et][3] + pb.w;
    short4v st = {(short)f2b(v0), (short)f2b(v1), (short)f2b(v2), (short)f2b(v3)};
    *(short4v*)(wout + gbase + (size_t)tg * 128 + e) = st;
    float s0 = v0, s1 = v1, s2 = v2, s3 = v3;
#pragma unroll
    for (int m = 1; m <= 8; m <<= 1) {
      s0 += __shfl_xor(s0, m, 64);
      s1 += __shfl_xor(s1, m, 64);
      s2 += __shfl_xor(s2, m, 64);
      s3 += __shfl_xor(s3, m, 64);
    }
    if (ln == 0) {
      float4 sv = {s0, s1, s2, s3};
      *(float4*)&sred[wv * 128 + e] = sv;
    }
  }
  __syncthreads();
  if (tid < 128) {
    float tot = sred[tid] + sred[128 + tid] + sred[256 + tid] + sred[384 + tid];
    sbuf[((size_t)sig * 4 + (blockIdx.x & 3)) * 128 + tid] = tot;
  }
}

// ---------------- SE gate (slim) ----------------
__global__ __launch_bounds__(128) void k_se(const float* __restrict__ sbuf,
                                            const float* __restrict__ w1, const float* __restrict__ b1,
                                            const float* __restrict__ w2, const float* __restrict__ b2,
                                            float* __restrict__ abuf) {
  int sig = blockIdx.x;
  __shared__ float sm[128];
  __shared__ float hh[32];
  int tid = threadIdx.x;
  const float* sp = sbuf + (size_t)sig * 4 * 128;
  sm[tid] = (sp[tid] + sp[128 + tid] + sp[256 + tid] + sp[384 + tid]) * (1.0f / 256.0f);
  __syncthreads();
  if (tid < 32) {
    float acc = b1[tid];
    for (int d = 0; d < 128; ++d) acc += w1[tid * 128 + d] * sm[d];
    hh[tid] = fmaxf(acc, 0.0f);
  }
  __syncthreads();
  float acc = b2[tid];
#pragma unroll
  for (int r = 0; r < 32; ++r) acc += w2[tid * 32 + r] * hh[r];
  abuf[sig * 128 + tid] = 1.0f / (1.0f + expf(-acc));
}

// ---------------- final update + mean over M -> xe2 fp32 + xe2bf bf16 ----------------
__global__ __launch_bounds__(256) void k_reduce2(const unsigned short* __restrict__ u,
                                                 const unsigned short* __restrict__ w,
                                                 const float* __restrict__ abuf, float* __restrict__ xe2,
                                                 unsigned short* __restrict__ xe2bf) {
  int i = blockIdx.x * 256 + threadIdx.x;
  int d0 = (i & 15) * 8;
  int t = (i >> 4) & 255;
  int b = i >> 12;
  float acc[8] = {0.f, 0.f, 0.f, 0.f, 0.f, 0.f, 0.f, 0.f};
#pragma unroll 4
  for (int m = 0; m < 12; ++m) {
    size_t base = ((size_t)(b * 12 + m) * 256 + t) * 128 + d0;
    short8 u8 = *(const short8*)(u + base);
    short8 w8 = *(const short8*)(w + base);
    float4 a0 = *(const float4*)&abuf[(b * 12 + m) * 128 + d0];
    float4 a1 = *(const float4*)&abuf[(b * 12 + m) * 128 + d0 + 4];
    float av[8] = {a0.x, a0.y, a0.z, a0.w, a1.x, a1.y, a1.z, a1.w};
#pragma unroll
    for (int j = 0; j < 8; ++j)
      acc[j] += b2f((unsigned short)u8[j]) + b2f((unsigned short)w8[j]) * av[j];
  }
  size_t off = (size_t)b * 32768 + (size_t)t * 128 + d0;
  float4 o0 = {acc[0] / 12.f, acc[1] / 12.f, acc[2] / 12.f, acc[3] / 12.f};
  float4 o1 = {acc[4] / 12.f, acc[5] / 12.f, acc[6] / 12.f, acc[7] / 12.f};
  *(float4*)(xe2 + off) = o0;
  *(float4*)(xe2 + off + 4) = o1;
  short8 ob;
#pragma unroll
  for (int j = 0; j < 8; ++j) ob[j] = (short)f2b(acc[j] / 12.f);
  *(short8*)(xe2bf + off) = ob;
}

// ---------------- mamba: in-projection via MFMA, zero-LDS -> bf16 xz[t][e] ----------------
__global__ __launch_bounds__(256) void k_inproj(const unsigned short* __restrict__ xe2bf,
                                                const unsigned short* __restrict__ inwbf,
                                                unsigned short* __restrict__ xz) {
  int blk = blockIdx.x;
  int b = blk >> 3;
  int tt = (blk >> 1) & 3;
  int eh = blk & 1;
  int t0 = tt * 64, e0 = eh * 256;
  int tid = threadIdx.x;
  int wv = tid >> 6, ln = tid & 15, q = (tid >> 4) & 3;
  int t = t0 + wv * 16 + ln;
  const unsigned short* xrow = xe2bf + ((size_t)b * 256 + t) * 128 + q * 8;
  short8 bfrag[4];
#pragma unroll
  for (int kc = 0; kc < 4; ++kc) bfrag[kc] = *(const short8*)(xrow + kc * 32);
  float4v acc[16];
#pragma unroll
  for (int et = 0; et < 16; ++et) acc[et] = (float4v){0.f, 0.f, 0.f, 0.f};
#pragma unroll
  for (int et = 0; et < 16; ++et) {
    const unsigned short* arow = inwbf + (size_t)(e0 + et * 16 + ln) * 128 + q * 8;
#pragma unroll
    for (int kc = 0; kc < 4; ++kc) {
      short8 af = *(const short8*)(arow + kc * 32);
      acc[et] = __builtin_amdgcn_mfma_f32_16x16x32_bf16(af, bfrag[kc], acc[et], 0, 0, 0);
    }
  }
  unsigned short* orow = xz + ((size_t)b * 256 + t) * 512 + e0 + q * 4;
#pragma unroll
  for (int et = 0; et < 16; ++et) {
    short4v st = {(short)f2b(acc[et][0]), (short)f2b(acc[et][1]),
                  (short)f2b(acc[et][2]), (short)f2b(acc[et][3])};
    *(short4v*)(orow + et * 16) = st;
  }
}

// ---------------- mamba: fused causal conv+SiLU -> x-projection MFMA; writes xc + dbl ----------------
// grid 256 = b(64) x tq(4); LDS xis[67][264] two-phase overlay (xi rows -> xc rows)
__global__ __launch_bounds__(256) void k_xproj(const unsigned short* __restrict__ xz,
                                               const float* __restrict__ cw, const float* __restrict__ cb,
                                               const unsigned short* __restrict__ xwbf,
                                               unsigned short* __restrict__ xcg,
                                               float* __restrict__ dbl) {
  __shared__ unsigned short xis[67 * 264];
  int blk = blockIdx.x;
  int b = blk >> 2;
  int tq = blk & 3;
  int t0 = tq * 64;
  int tid = threadIdx.x;

  // stage xi rows t0-3 .. t0+63
  const short8 ZV = {0, 0, 0, 0, 0, 0, 0, 0};
  for (int idx = tid; idx < 2144; idx += 256) {
    int row = idx >> 5, cu = idx & 31;
    int t = t0 - 3 + row;
    short8 v = ZV;
    if (t >= 0) v = *(const short8*)(xz + ((size_t)b * 256 + t) * 512 + cu * 8);
    *(short8*)(xis + row * 264 + cu * 8) = v;
  }
  __syncthreads();

  // conv weights for this thread's 8 channels
  int cu = tid & 31;
  int rb = tid >> 5;      // 0..7
  int c8 = cu * 8;
  float wl[4][8], bl[8];
#pragma unroll
  for (int j = 0; j < 8; ++j) {
    float4 w4 = *(const float4*)&cw[(c8 + j) * 4];
    wl[0][j] = w4.x; wl[1][j] = w4.y; wl[2][j] = w4.z; wl[3][j] = w4.w;
    bl[j] = cb[c8 + j];
  }

  short8 vv[4];
  // Phase A: xc rows 0..31 (reads xis rows 0..34)
#pragma unroll
  for (int s = 0; s < 4; ++s) {
    int r = rb + s * 8;
    float acc[8];
#pragma unroll
    for (int j = 0; j < 8; ++j) acc[j] = bl[j];
#pragma unroll
    for (int k = 0; k < 4; ++k) {
      short8 u8 = *(const short8*)(xis + (r + k) * 264 + c8);
#pragma unroll
      for (int j = 0; j < 8; ++j) acc[j] += b2f((unsigned short)u8[j]) * wl[k][j];
    }
#pragma unroll
    for (int j = 0; j < 8; ++j)
      vv[s][j] = (short)f2b(acc[j] / (1.0f + __expf(-acc[j])));
    *(short8*)(xcg + ((size_t)b * 256 + t0 + r) * 256 + c8) = vv[s];
  }
  __syncthreads();
#pragma unroll
  for (int s = 0; s < 4; ++s)
    *(short8*)(xis + (rb + s * 8) * 264 + c8) = vv[s];

  // Phase B: xc rows 32..63 (reads xis rows 32..66)
#pragma unroll
  for (int s = 0; s < 4; ++s) {
    int r = 32 + rb + s * 8;
    float acc[8];
#pragma unroll
    for (int j = 0; j < 8; ++j) acc[j] = bl[j];
#pragma unroll
    for (int k = 0; k < 4; ++k) {
      short8 u8 = *(const short8*)(xis + (r + k) * 264 + c8);
#pragma unroll
      for (int j = 0; j < 8; ++j) acc[j] += b2f((unsigned short)u8[j]) * wl[k][j];
    }
#pragma unroll
    for (int j = 0; j < 8; ++j)
      vv[s][j] = (short)f2b(acc[j] / (1.0f + __expf(-acc[j])));
    *(short8*)(xcg + ((size_t)b * 256 + t0 + r) * 256 + c8) = vv[s];
  }
  __syncthreads();
#pragma unroll
  for (int s = 0; s < 4; ++s)
    *(short8*)(xis + (32 + rb + s * 8) * 264 + c8) = vv[s];
  __syncthreads();

  // MFMA: dbl[t][k] = sum_c xw[k][c] * xc[t][c]
  int wv = tid >> 6, ln = tid & 15, q = (tid >> 4) & 3;
  int tl = wv * 16 + ln;
  short8 bfrag[8];
#pragma unroll
  for (int kc = 0; kc < 8; ++kc)
    bfrag[kc] = *(const short8*)(xis + tl * 264 + kc * 32 + q * 8);
  float4v acc[3];
#pragma unroll
  for (int et = 0; et < 3; ++et) acc[et] = (float4v){0.f, 0.f, 0.f, 0.f};
#pragma unroll
  for (int et = 0; et < 3; ++et) {
    const unsigned short* arow = xwbf + (size_t)(et * 16 + ln) * 256 + q * 8;
#pragma unroll
    for (int kc = 0; kc < 8; ++kc) {
      short8 af = *(const short8*)(arow + kc * 32);
      acc[et] = __builtin_amdgcn_mfma_f32_16x16x32_bf16(af, bfrag[kc], acc[et], 0, 0, 0);
    }
  }
  float* drow = dbl + ((size_t)b * 256 + t0 + tl) * 40;
#pragma unroll
  for (int et = 0; et < 3; ++et)
#pragma unroll
    for (int r = 0; r < 4; ++r) {
      int k = et * 16 + q * 4 + r;
      if (k < 40) drow[k] = acc[et][r];
    }
}

// ---------------- mamba: fused dt + selective scan + y-finalize ----------------
__global__ __launch_bounds__(128) void k_scan2(const float* __restrict__ dbl,
                                               const unsigned short* __restrict__ xc,
                                               const unsigned short* __restrict__ xz,
                                               const float* __restrict__ Alog,
                                               const float* __restrict__ dtw, const float* __restrict__ dtbv,
                                               const float* __restrict__ Dp, unsigned short* __restrict__ y) {
  __shared__ float ds[32][40];
  __shared__ float dxs[32][32][4];
  __shared__ float yl[32][32];
  __shared__ float dtwL[32][8];
  __shared__ float dtbL[32];
  __shared__ float DpL[32];

  int b = blockIdx.x >> 3;
  int c0 = (blockIdx.x & 7) * 32;
  int tid = threadIdx.x;

  for (int idx = tid; idx < 256; idx += 128) dtwL[idx >> 3][idx & 7] = dtw[(c0 + (idx >> 3)) * 8 + (idx & 7)];
  if (tid < 32) { dtbL[tid] = dtbv[c0 + tid]; DpL[tid] = Dp[c0 + tid]; }

  int lane = tid & 63;
  int wv = tid >> 6;
  int c_loc = wv * 16 + (lane >> 2);
  int c = c0 + c_loc;
  int sblk = (lane & 3) * 4;

  float4 Al = *(const float4*)&Alog[c * 16 + sblk];
  float A[4] = {-__expf(Al.x), -__expf(Al.y), -__expf(Al.z), -__expf(Al.w)};
  float h[4] = {0.f, 0.f, 0.f, 0.f};

  const float* dbp = dbl + (size_t)b * 10240;
  const unsigned short* xcp = xc + (size_t)b * 65536;
  const unsigned short* xzp = xz + (size_t)b * 131072;
  unsigned short* yp = y + (size_t)b * 65536;

  for (int chk = 0; chk < 8; ++chk) {
    int t0c = chk * 32;
    for (int idx = tid; idx < 1280; idx += 128) ((float*)ds)[idx] = dbp[t0c * 40 + idx];
    for (int idx = tid; idx < 512; idx += 128) {
      int t = idx >> 4, cc2 = (idx & 15) * 2;
      ushort2 xv = *(const ushort2*)&xcp[(size_t)(t0c + t) * 256 + c0 + cc2];
      ushort2 zv = *(const ushort2*)&xzp[(size_t)(t0c + t) * 512 + 256 + c0 + cc2];
      dxs[t][cc2][1] = b2f(xv.x);
      dxs[t][cc2 + 1][1] = b2f(xv.y);
      dxs[t][cc2][2] = b2f(zv.x);
      dxs[t][cc2 + 1][2] = b2f(zv.y);
    }
    __syncthreads();
    for (int idx = tid; idx < 1024; idx += 128) {
      int t = idx >> 5, cc = idx & 31;
      const float* dr = ds[t];
      const float* wr = dtwL[cc];
      float acc = dtbL[cc];
#pragma unroll
      for (int j = 0; j < 8; ++j) acc += wr[j] * dr[j];
      dxs[t][cc][0] = (acc > 20.0f) ? acc : __logf(1.0f + __expf(acc));
    }
    __syncthreads();
#pragma unroll 4
    for (int t = 0; t < 32; ++t) {
      float4 dx = *(const float4*)&dxs[t][c_loc][0];
      float4 Bv = *(const float4*)&ds[t][8 + sblk];
      float4 Cv = *(const float4*)&ds[t][24 + sblk];
      float dtv = dx.x;
      float bx = dtv * dx.y;
      h[0] = __expf(dtv * A[0]) * h[0] + Bv.x * bx;
      h[1] = __expf(dtv * A[1]) * h[1] + Bv.y * bx;
      h[2] = __expf(dtv * A[2]) * h[2] + Bv.z * bx;
      h[3] = __expf(dtv * A[3]) * h[3] + Bv.w * bx;
      float p = h[0] * Cv.x;
      p = fmaf(h[1], Cv.y, p);
      p = fmaf(h[2], Cv.z, p);
      p = fmaf(h[3], Cv.w, p);
      p += qxor1(p);
      p += qxor2(p);
      if ((lane & 3) == 0) yl[t][c_loc] = p;
    }
    __syncthreads();
    for (int idx = tid; idx < 512; idx += 128) {
      int t = idx >> 4, cc2 = (idx & 15) * 2;
      float p0 = yl[t][cc2], p1 = yl[t][cc2 + 1];
      float x0 = dxs[t][cc2][1], x1 = dxs[t][cc2 + 1][1];
      float z0 = dxs[t][cc2][2], z1 = dxs[t][cc2 + 1][2];
      float s0 = z0 / (1.0f + __expf(-z0));
      float s1 = z1 / (1.0f + __expf(-z1));
      ushort2 o = {f2b((p0 + DpL[cc2] * x0) * s0), f2b((p1 + DpL[cc2 + 1] * x1) * s1)};
      *(ushort2*)&yp[(size_t)(t0c + t) * 256 + c0 + cc2] = o;
    }
    __syncthreads();
  }
}

// ---------------- mamba: MFMA out-projection + residual + LayerNorm, zero-LDS ----------------
__global__ __launch_bounds__(128) void k_outln(const unsigned short* __restrict__ yb,
                                               const unsigned short* __restrict__ owbf,
                                               float* __restrict__ xe2, unsigned short* __restrict__ xe2bf,
                                               const float* __restrict__ g, const float* __restrict__ bb) {
  int blk = blockIdx.x;
  int b = blk >> 3;
  int t0 = (blk & 7) * 32;
  int tid = threadIdx.x;
  int wv = tid >> 6, ln = tid & 15, q = (tid >> 4) & 3;
  int t = t0 + wv * 16 + ln;

  const unsigned short* yrow = yb + ((size_t)b * 256 + t) * 256 + q * 8;
  short8 bfrag[8];
#pragma unroll
  for (int kc = 0; kc < 8; ++kc) bfrag[kc] = *(const short8*)(yrow + kc * 32);

  float4v acc[8];
#pragma unroll
  for (int et = 0; et < 8; ++et) acc[et] = (float4v){0.f, 0.f, 0.f, 0.f};
#pragma unroll
  for (int et = 0; et < 8; ++et) {
    const unsigned short* arow = owbf + (size_t)(et * 16 + ln) * 256 + q * 8;
#pragma unroll
    for (int kc = 0; kc < 8; ++kc) {
      short8 af = *(const short8*)(arow + kc * 32);
      acc[et] = __builtin_amdgcn_mfma_f32_16x16x32_bf16(af, bfrag[kc], acc[et], 0, 0, 0);
    }
  }

  float* xrow = xe2 + ((size_t)b * 256 + t) * 128;
  float vals[8][4];
  float s1 = 0.f, s2 = 0.f;
#pragma unroll
  for (int et = 0; et < 8; ++et) {
    float4 res = *(const float4*)(xrow + et * 16 + q * 4);
    float rv[4] = {res.x, res.y, res.z, res.w};
#pragma unroll
    for (int r = 0; r < 4; ++r) {
      float v = acc[et][r] + rv[r];
      vals[et][r] = v;
      s1 += v;
      s2 += v * v;
    }
  }
  s1 += __shfl_xor(s1, 16, 64);
  s1 += __shfl_xor(s1, 32, 64);
  s2 += __shfl_xor(s2, 16, 64);
  s2 += __shfl_xor(s2, 32, 64);
  float mu = s1 * (1.0f / 128.0f);
  float rs = rsqrtf(s2 * (1.0f / 128.0f) - mu * mu + 1e-5f);

  unsigned short* brow = xe2bf + ((size_t)b * 256 + t) * 128;
#pragma unroll
  for (int et = 0; et < 8; ++et) {
    int d = et * 16 + q * 4;
    float4 g4 = *(const float4*)(g + d);
    float4 b4 = *(const float4*)(bb + d);
    float o0 = (vals[et][0] - mu) * rs * g4.x + b4.x;
    float o1 = (vals[et][1] - mu) * rs * g4.y + b4.y;
    float o2 = (vals[et][2] - mu) * rs * g4.z + b4.z;
    float o3 = (vals[et][3] - mu) * rs * g4.w + b4.w;
    float4 of = {o0, o1, o2, o3};
    *(float4*)(xrow + d) = of;
    short4v ob = {(short)f2b(o0), (short)f2b(o1), (short)f2b(o2), (short)f2b(o3)};
    *(short4v*)(brow + d) = ob;
  }
}

// ---------------- xflat transpose (+bf16 copy, + pred bias init) ----------------
__global__ __launch_bounds__(256) void k_xflat(const float* __restrict__ xe2, float* __restrict__ out,
                                               unsigned short* __restrict__ outbf,
                                               const float* __restrict__ fcb, float* __restrict__ pred) {
  int b = blockIdx.x >> 5;
  int blk = blockIdx.x & 31;
  int t0 = (blk >> 2) * 32, d0 = (blk & 3) * 32;
  __shared__ float tile[32][33];
  int tid = threadIdx.x;
  if (blockIdx.x == 0) {
    for (int i = tid; i < 1152; i += 256) pred[i] = fcb[i % 18];
  }
#pragma unroll
  for (int q = 0; q < 4; ++q) {
    int t = (tid >> 5) + q * 8, dd = tid & 31;
    tile[t][dd] = xe2[(size_t)b * 32768 + (size_t)(t0 + t) * 128 + d0 + dd];
  }
  __syncthreads();
#pragma unroll
  for (int q = 0; q < 4; ++q) {
    int dd = (tid >> 5) + q * 8, t = tid & 31;
    float v = tile[t][dd];
    size_t o = (size_t)b * 32768 + (size_t)(d0 + dd) * 256 + t0 + t;
    out[o] = v;
    outbf[o] = f2b(v);
  }
}

// ---------------- final FC via MFMA: pred[b,c] += sum_k fw[c,k]*xflat[b,k] ----------------
__global__ __launch_bounds__(256) void k_fc(const unsigned short* __restrict__ xflatbf,
                                            const unsigned short* __restrict__ fwbf,
                                            float* __restrict__ pred) {
  int kb = blockIdx.x;          // 128 blocks, K=256 each
  int k0 = kb * 256;
  int tid = threadIdx.x;
  int wv = tid >> 6, ln = tid & 15, q = (tid >> 4) & 3;
  int b = wv * 16 + ln;
  const unsigned short* xrow = xflatbf + (size_t)b * 32768 + k0 + q * 8;
  float4v acc[2];
  acc[0] = (float4v){0.f, 0.f, 0.f, 0.f};
  acc[1] = (float4v){0.f, 0.f, 0.f, 0.f};
#pragma unroll
  for (int kc = 0; kc < 8; ++kc) {
    short8 bfrag = *(const short8*)(xrow + kc * 32);
#pragma unroll
    for (int et = 0; et < 2; ++et) {
      short8 af = *(const short8*)(fwbf + (size_t)(et * 16 + ln) * 32768 + k0 + kc * 32 + q * 8);
      acc[et] = __builtin_amdgcn_mfma_f32_16x16x32_bf16(af, bfrag, acc[et], 0, 0, 0);
    }
  }
#pragma unroll
  for (int et = 0; et < 2; ++et)
#pragma unroll
    for (int r = 0; r < 4; ++r) {
      int c = et * 16 + q * 4 + r;
      if (c < 18) atomicAdd(&pred[b * 18 + c], acc[et][r]);
    }
}

extern "C" void kernel_launch(void* const* d_in, const int* in_sizes, int n_in,
                              void* d_out, int out_size, void* d_ws, size_t ws_size,
                              hipStream_t stream) {
  (void)in_sizes; (void)n_in; (void)out_size; (void)ws_size;
  const float* inp    = (const float*)d_in[0];
  const float* emb_w  = (const float*)d_in[1];
  const float* emb_b  = (const float*)d_in[2];
  const float* dw_w   = (const float*)d_in[3];
  const float* dw_b   = (const float*)d_in[4];
  const float* pw_w   = (const float*)d_in[5];
  const float* pw_b   = (const float*)d_in[6];
  const float* se_w1  = (const float*)d_in[7];
  const float* se_b1  = (const float*)d_in[8];
  const float* se_w2  = (const float*)d_in[9];
  const float* se_b2  = (const float*)d_in[10];
  const float* in_w   = (const float*)d_in[11];
  const float* conv_w = (const float*)d_in[12];
  const float* conv_b = (const float*)d_in[13];
  const float* xp_w   = (const float*)d_in[14];
  const float* dt_w   = (const float*)d_in[15];
  const float* dt_b   = (const float*)d_in[16];
  const float* Alog   = (const float*)d_in[17];
  const float* Dp     = (const float*)d_in[18];
  const float* out_w  = (const float*)d_in[19];
  const float* ln_g   = (const float*)d_in[20];
  const float* ln_b   = (const float*)d_in[21];
  const float* fc_w   = (const float*)d_in[22];
  const float* fc_b   = (const float*)d_in[23];

  char* ws = (char*)d_ws;
  unsigned short* U0 = (unsigned short*)(ws);
  unsigned short* W0 = (unsigned short*)(ws + 50331648);
  unsigned short* U1 = (unsigned short*)(ws + 100663296);
  unsigned short* W1 = (unsigned short*)(ws + 150994944);
  float* abuf = (float*)(ws + 201326592);
  float* sbuf = abuf + 98304;
  unsigned short* xz = (unsigned short*)(ws);                 // bf16 (U0 region)
  unsigned short* xc = (unsigned short*)(ws + 33554432);      // bf16
  unsigned short* yb = (unsigned short*)(ws + 50331648);      // bf16 (W0 region)
  float* xe2 = (float*)(ws + 100663296);                      // fp32 (U1 head)
  unsigned short* xflatbf = (unsigned short*)(ws + 109051904);// bf16 4.2MB (U1 tail, free after block stage)
  unsigned short* fwbf = (unsigned short*)(ws + 113246208);   // bf16 2MB padded [32][32768]
  float* dbl = (float*)(ws + 150994944);                      // fp32 (W1 region)
  unsigned short* xe2bf = (unsigned short*)(ws + 153616384);  // bf16 4MB

  float* xflat = (float*)d_out;
  float* pred  = xflat + (size_t)64 * 32768;
  unsigned short* pwbf  = (unsigned short*)d_out;   // weight scratch until k_xflat
  unsigned short* inwbf = pwbf + 49152;
  unsigned short* owbf  = inwbf + 131072;
  unsigned short* xwbf  = owbf + 65536;
  unsigned short* ewbf  = xwbf + 24576;

  k_cvt<<<1072, 256, 0, stream>>>(pw_w, in_w, out_w, xp_w, emb_w, pwbf);
  k_emb<<<768, 256, 0, stream>>>(inp, ewbf, emb_b, U0);

  k_blk<0><<<3072, 256, 0, stream>>>(U0, U0, abuf, dw_w, dw_b, pwbf, pw_b, U0, W0, sbuf);
  k_se<<<768, 128, 0, stream>>>(sbuf, se_w1, se_b1, se_w2, se_b2, abuf);
  k_blk<1><<<3072, 256, 0, stream>>>(U0, W0, abuf, dw_w + 640, dw_b + 128, pwbf + 16384, pw_b + 128,
                                     U1, W1, sbuf);
  k_se<<<768, 128, 0, stream>>>(sbuf, se_w1 + 4096, se_b1 + 32, se_w2 + 4096, se_b2 + 128, abuf);
  k_blk<1><<<3072, 256, 0, stream>>>(U1, W1, abuf, dw_w + 1280, dw_b + 256, pwbf + 32768, pw_b + 256,
                                     U0, W0, sbuf);
  k_se<<<768, 128, 0, stream>>>(sbuf, se_w1 + 8192, se_b1 + 64, se_w2 + 8192, se_b2 + 256, abuf);

  k_reduce2<<<1024, 256, 0, stream>>>(U0, W0, abuf, xe2, xe2bf);
  k_cvt2<<<4096, 256, 0, stream>>>(fc_w, fwbf);

  for (int i = 0; i < 2; ++i) {
    k_inproj<<<512, 256, 0, stream>>>(xe2bf, inwbf + i * 65536, xz);
    k_xproj<<<256, 256, 0, stream>>>(xz, conv_w + i * 1024, conv_b + i * 256,
                                     xwbf + i * 12288, xc, dbl);
    k_scan2<<<512, 128, 0, stream>>>(dbl, xc, xz, Alog + i * 4096,
                                     dt_w + i * 2048, dt_b + i * 256, Dp + i * 256, yb);
    k_outln<<<512, 128, 0, stream>>>(yb, owbf + i * 32768, xe2, xe2bf,
                                     ln_g + i * 128, ln_b + i * 128);
  }

  k_xflat<<<2048, 256, 0, stream>>>(xe2, xflat, xflatbf, fc_b, pred);
  k_fc<<<128, 256, 0, stream>>>(xflatbf, fwbf, pred);
}

// Round 14
// 601.175 us; speedup vs baseline: 1.3053x; 1.2043x over previous
//
#include <hip/hip_runtime.h>
#include <math.h>

#define LL 2048
#define MM 12
#define DD 128
#define TP 256   // T
#define MEGA_LDS 78464

typedef short short8 __attribute__((ext_vector_type(8)));
typedef short short4v __attribute__((ext_vector_type(4)));
typedef float float4v __attribute__((ext_vector_type(4)));

static __device__ __forceinline__ unsigned short f2b(float f) {
  union { float f; unsigned int u; } x; x.f = f;
  unsigned int r = x.u + 0x7fffu + ((x.u >> 16) & 1u);
  return (unsigned short)(r >> 16);
}
static __device__ __forceinline__ float b2f(unsigned short u) {
  union { unsigned int u; float f; } x; x.u = ((unsigned int)u) << 16;
  return x.f;
}
static __device__ __forceinline__ float qxor1(float x) {
  int r = __builtin_amdgcn_mov_dpp(__builtin_bit_cast(int, x), 0xB1, 0xF, 0xF, true);
  return __builtin_bit_cast(float, r);
}
static __device__ __forceinline__ float qxor2(float x) {
  int r = __builtin_amdgcn_mov_dpp(__builtin_bit_cast(int, x), 0x4E, 0xF, 0xF, true);
  return __builtin_bit_cast(float, r);
}

// ---------------- convert weights to bf16 (pw, in_w, out_w, padded xp_w, padded ew) ----------------
__global__ __launch_bounds__(256) void k_cvt(const float* __restrict__ pw_w, const float* __restrict__ in_w,
                                             const float* __restrict__ out_w, const float* __restrict__ xp_w,
                                             const float* __restrict__ ew,
                                             unsigned short* __restrict__ pwbf) {
  int i = blockIdx.x * 256 + threadIdx.x;
  if (i < 49152) { pwbf[i] = f2b(pw_w[i]); return; }
  int i2 = i - 49152;
  if (i2 < 131072) { pwbf[i] = f2b(in_w[i2]); return; }
  int i3 = i2 - 131072;
  if (i3 < 65536) { pwbf[i] = f2b(out_w[i3]); return; }
  int i4 = i3 - 65536;
  if (i4 < 24576) {
    int layer = (i4 < 12288) ? 0 : 1;
    int rem = i4 - layer * 12288;
    int k = rem >> 8, c = rem & 255;
    float v = (k < 40) ? xp_w[layer * 10240 + k * 256 + c] : 0.0f;
    pwbf[i] = f2b(v);
    return;
  }
  int i5 = i4 - 24576;
  if (i5 < 4096) {
    int d = i5 >> 5, k = i5 & 31;
    float v = (k < 16) ? ew[d * 16 + k] : 0.0f;
    pwbf[i] = f2b(v);
  }
}

// ---------------- convert fc_w -> bf16 padded [32][32768] ----------------
__global__ __launch_bounds__(256) void k_cvt2(const float* __restrict__ fw, unsigned short* __restrict__ fwbf) {
  int i = blockIdx.x * 256 + threadIdx.x;
  int m = i >> 15, k = i & 32767;
  fwbf[i] = f2b((m < 18) ? fw[m * 32768 + k] : 0.0f);
}

// ---------------- embedding via MFMA ----------------
__global__ __launch_bounds__(256) void k_emb(const float* __restrict__ inp,
                                             const unsigned short* __restrict__ ewbf,
                                             const float* __restrict__ eb,
                                             unsigned short* __restrict__ xe) {
  int sig = blockIdx.x;
  int b = sig / MM, m = sig % MM;
  __shared__ float xs[LL];
  const float* ib = inp + (size_t)b * LL * MM + m;
  int tid = threadIdx.x;
  for (int i = tid; i < LL; i += 256) xs[i] = ib[(size_t)i * MM];
  __syncthreads();
  int wv = tid >> 6, ln = tid & 15, q = (tid >> 4) & 3;
  short8 af[8];
#pragma unroll
  for (int et = 0; et < 8; ++et)
    af[et] = *(const short8*)(ewbf + (et * 16 + ln) * 32 + q * 8);
#pragma unroll
  for (int pass = 0; pass < 4; ++pass) {
    int t = pass * 64 + wv * 16 + ln;
    int l0 = t * 8 - 4;
    short8 bfrag;
#pragma unroll
    for (int j = 0; j < 8; ++j) {
      int k = q * 8 + j;
      int l = l0 + k;
      float v = (k < 16 && l >= 0 && l < LL) ? xs[l] : 0.0f;
      bfrag[j] = (short)f2b(v);
    }
    float4v acc[8];
#pragma unroll
    for (int et = 0; et < 8; ++et) {
      acc[et] = (float4v){0.f, 0.f, 0.f, 0.f};
      acc[et] = __builtin_amdgcn_mfma_f32_16x16x32_bf16(af[et], bfrag, acc[et], 0, 0, 0);
    }
    unsigned short* orow = xe + (size_t)sig * 32768 + (size_t)t * 128;
#pragma unroll
    for (int et = 0; et < 8; ++et) {
      int e = et * 16 + q * 4;
      float4 pb = *(const float4*)&eb[e];
      short4v st = {(short)f2b(acc[et][0] + pb.x), (short)f2b(acc[et][1] + pb.y),
                    (short)f2b(acc[et][2] + pb.z), (short)f2b(acc[et][3] + pb.w)};
      *(short4v*)(orow + e) = st;
    }
  }
}

// ---------------- MEGA block stage: all 3 layers + SE, signal resident in LDS ----------------
// grid 768 x 512 threads; dynamic LDS 78464 B:
//   us [256][136] bf16 @0 (69632) | dwT[5][128] @69632 | dwbL[128] | pwbL[128] |
//   sred[8][128] | smv[128] | hh[32] | aL[128]
__global__ __launch_bounds__(512) void k_mega(const unsigned short* __restrict__ u0,
                                              const float* __restrict__ dww, const float* __restrict__ dwb,
                                              const unsigned short* __restrict__ pwbf,
                                              const float* __restrict__ pwb,
                                              const float* __restrict__ w1, const float* __restrict__ b1,
                                              const float* __restrict__ w2, const float* __restrict__ b2,
                                              unsigned short* __restrict__ uout) {
  extern __shared__ char smemraw[];
  unsigned short* us = (unsigned short*)smemraw;
  float* dwT  = (float*)(smemraw + 69632);
  float* dwbL = dwT + 640;
  float* pwbL = dwbL + 128;
  float* sred = pwbL + 128;
  float* smv  = sred + 1024;
  float* hh   = smv + 128;
  float* aL   = hh + 32;

  int sig = blockIdx.x;
  int tid = threadIdx.x;
  const size_t gbase = (size_t)sig * 32768;
  int cu = tid & 15;
  int r0 = tid >> 4;   // 0..31

#pragma unroll
  for (int p = 0; p < 8; ++p) {
    int t = p * 32 + r0;
    short8 v = *(const short8*)(u0 + gbase + (size_t)t * 128 + cu * 8);
    *(short8*)(us + t * 136 + cu * 8) = v;
  }

  int wv = tid >> 6;
  int ln = tid & 15;
  int q  = (tid >> 4) & 3;
  int tb = wv * 32;

  for (int layer = 0; layer < 3; ++layer) {
    __syncthreads();
    for (int i = tid; i < 640; i += 512) dwT[(i % 5) * 128 + (i / 5)] = dww[layer * 640 + i];
    if (tid < 128) { dwbL[tid] = dwb[layer * 128 + tid]; pwbL[tid] = pwb[layer * 128 + tid]; }
    __syncthreads();

    const unsigned short* pwL = pwbf + layer * 16384;
    float4v acc[2][8];
#pragma unroll
    for (int tl = 0; tl < 2; ++tl)
#pragma unroll
      for (int et = 0; et < 8; ++et) acc[tl][et] = (float4v){0.f, 0.f, 0.f, 0.f};

#pragma unroll
    for (int kc = 0; kc < 4; ++kc) {
      int dc = kc * 32 + q * 8;
      short8 af[8];
#pragma unroll
      for (int et = 0; et < 8; ++et)
        af[et] = *(const short8*)(pwL + (size_t)(et * 16 + ln) * 128 + dc);
      float wt[5][8], bl8[8];
#pragma unroll
      for (int k = 0; k < 5; ++k) {
        float4 wa = *(const float4*)&dwT[k * 128 + dc];
        float4 wb = *(const float4*)&dwT[k * 128 + dc + 4];
        wt[k][0] = wa.x; wt[k][1] = wa.y; wt[k][2] = wa.z; wt[k][3] = wa.w;
        wt[k][4] = wb.x; wt[k][5] = wb.y; wt[k][6] = wb.z; wt[k][7] = wb.w;
      }
      {
        float4 ba = *(const float4*)&dwbL[dc];
        float4 bb2 = *(const float4*)&dwbL[dc + 4];
        bl8[0] = ba.x; bl8[1] = ba.y; bl8[2] = ba.z; bl8[3] = ba.w;
        bl8[4] = bb2.x; bl8[5] = bb2.y; bl8[6] = bb2.z; bl8[7] = bb2.w;
      }
#pragma unroll
      for (int tl = 0; tl < 2; ++tl) {
        int t = tb + tl * 16 + ln;
        float a8[8];
#pragma unroll
        for (int j = 0; j < 8; ++j) a8[j] = bl8[j];
#pragma unroll
        for (int k = 0; k < 5; ++k) {
          int tt = t - 2 + k;
          if (tt >= 0 && tt < 256) {
            short8 u8 = *(const short8*)(us + tt * 136 + dc);
#pragma unroll
            for (int j = 0; j < 8; ++j) a8[j] += b2f((unsigned short)u8[j]) * wt[k][j];
          }
        }
        short8 bf;
#pragma unroll
        for (int j = 0; j < 8; ++j)
          bf[j] = (short)f2b(0.5f * a8[j] * (1.0f + erff(a8[j] * 0.70710678118654752f)));
#pragma unroll
        for (int et = 0; et < 8; ++et)
          acc[tl][et] = __builtin_amdgcn_mfma_f32_16x16x32_bf16(af[et], bf, acc[tl][et], 0, 0, 0);
      }
    }
    __syncthreads();   // all us reads done; sred free

    // SE t-partial sums -> sred
#pragma unroll
    for (int et = 0; et < 8; ++et) {
      int e = et * 16 + q * 4;
      float4 pb = *(const float4*)&pwbL[e];
      float sv0 = acc[0][et][0] + acc[1][et][0] + 2.0f * pb.x;
      float sv1 = acc[0][et][1] + acc[1][et][1] + 2.0f * pb.y;
      float sv2 = acc[0][et][2] + acc[1][et][2] + 2.0f * pb.z;
      float sv3 = acc[0][et][3] + acc[1][et][3] + 2.0f * pb.w;
#pragma unroll
      for (int m = 1; m <= 8; m <<= 1) {
        sv0 += __shfl_xor(sv0, m, 64);
        sv1 += __shfl_xor(sv1, m, 64);
        sv2 += __shfl_xor(sv2, m, 64);
        sv3 += __shfl_xor(sv3, m, 64);
      }
      if (ln == 0) {
        float4 sv = {sv0, sv1, sv2, sv3};
        *(float4*)&sred[wv * 128 + e] = sv;
      }
    }
    __syncthreads();
    if (tid < 128) {
      float s = 0.f;
#pragma unroll
      for (int w = 0; w < 8; ++w) s += sred[w * 128 + tid];
      smv[tid] = s * (1.0f / 256.0f);
    }
    __syncthreads();
    if (tid < 32) {
      float a1 = b1[layer * 32 + tid];
      for (int d = 0; d < 128; ++d) a1 += w1[layer * 4096 + tid * 128 + d] * smv[d];
      hh[tid] = fmaxf(a1, 0.0f);
    }
    __syncthreads();
    if (tid < 128) {
      float a2 = b2[layer * 128 + tid];
#pragma unroll
      for (int r = 0; r < 32; ++r) a2 += w2[layer * 4096 + tid * 32 + r] * hh[r];
      aL[tid] = 1.0f / (1.0f + expf(-a2));
    }
    __syncthreads();

    // u += w * a  (in LDS, disjoint per lane)
#pragma unroll
    for (int tl = 0; tl < 2; ++tl) {
      int t = tb + tl * 16 + ln;
#pragma unroll
      for (int et = 0; et < 8; ++et) {
        int e = et * 16 + q * 4;
        float4 pb = *(const float4*)&pwbL[e];
        float4 ga = *(const float4*)&aL[e];
        short4v u4 = *(short4v*)(us + t * 136 + e);
        short4v r;
        r[0] = (short)f2b(b2f((unsigned short)u4[0]) + (acc[tl][et][0] + pb.x) * ga.x);
        r[1] = (short)f2b(b2f((unsigned short)u4[1]) + (acc[tl][et][1] + pb.y) * ga.y);
        r[2] = (short)f2b(b2f((unsigned short)u4[2]) + (acc[tl][et][2] + pb.z) * ga.z);
        r[3] = (short)f2b(b2f((unsigned short)u4[3]) + (acc[tl][et][3] + pb.w) * ga.w);
        *(short4v*)(us + t * 136 + e) = r;
      }
    }
  }
  __syncthreads();
#pragma unroll
  for (int p = 0; p < 8; ++p) {
    int t = p * 32 + r0;
    short8 v = *(short8*)(us + t * 136 + cu * 8);
    *(short8*)(uout + gbase + (size_t)t * 128 + cu * 8) = v;
  }
}

// ---------------- mean over M -> xe2 fp32 + xe2bf bf16 ----------------
__global__ __launch_bounds__(256) void k_reduce2(const unsigned short* __restrict__ u,
                                                 float* __restrict__ xe2,
                                                 unsigned short* __restrict__ xe2bf) {
  int i = blockIdx.x * 256 + threadIdx.x;
  int d0 = (i & 15) * 8;
  int t = (i >> 4) & 255;
  int b = i >> 12;
  float acc[8] = {0.f, 0.f, 0.f, 0.f, 0.f, 0.f, 0.f, 0.f};
#pragma unroll 4
  for (int m = 0; m < 12; ++m) {
    size_t base = ((size_t)(b * 12 + m) * 256 + t) * 128 + d0;
    short8 u8 = *(const short8*)(u + base);
#pragma unroll
    for (int j = 0; j < 8; ++j) acc[j] += b2f((unsigned short)u8[j]);
  }
  size_t off = (size_t)b * 32768 + (size_t)t * 128 + d0;
  float4 o0 = {acc[0] / 12.f, acc[1] / 12.f, acc[2] / 12.f, acc[3] / 12.f};
  float4 o1 = {acc[4] / 12.f, acc[5] / 12.f, acc[6] / 12.f, acc[7] / 12.f};
  *(float4*)(xe2 + off) = o0;
  *(float4*)(xe2 + off + 4) = o1;
  short8 ob;
#pragma unroll
  for (int j = 0; j < 8; ++j) ob[j] = (short)f2b(acc[j] / 12.f);
  *(short8*)(xe2bf + off) = ob;
}

// ---------------- mamba: in-projection via MFMA, zero-LDS -> bf16 xz[t][e] ----------------
__global__ __launch_bounds__(256) void k_inproj(const unsigned short* __restrict__ xe2bf,
                                                const unsigned short* __restrict__ inwbf,
                                                unsigned short* __restrict__ xz) {
  int blk = blockIdx.x;
  int b = blk >> 3;
  int tt = (blk >> 1) & 3;
  int eh = blk & 1;
  int t0 = tt * 64, e0 = eh * 256;
  int tid = threadIdx.x;
  int wv = tid >> 6, ln = tid & 15, q = (tid >> 4) & 3;
  int t = t0 + wv * 16 + ln;
  const unsigned short* xrow = xe2bf + ((size_t)b * 256 + t) * 128 + q * 8;
  short8 bfrag[4];
#pragma unroll
  for (int kc = 0; kc < 4; ++kc) bfrag[kc] = *(const short8*)(xrow + kc * 32);
  float4v acc[16];
#pragma unroll
  for (int et = 0; et < 16; ++et) acc[et] = (float4v){0.f, 0.f, 0.f, 0.f};
#pragma unroll
  for (int et = 0; et < 16; ++et) {
    const unsigned short* arow = inwbf + (size_t)(e0 + et * 16 + ln) * 128 + q * 8;
#pragma unroll
    for (int kc = 0; kc < 4; ++kc) {
      short8 af = *(const short8*)(arow + kc * 32);
      acc[et] = __builtin_amdgcn_mfma_f32_16x16x32_bf16(af, bfrag[kc], acc[et], 0, 0, 0);
    }
  }
  unsigned short* orow = xz + ((size_t)b * 256 + t) * 512 + e0 + q * 4;
#pragma unroll
  for (int et = 0; et < 16; ++et) {
    short4v st = {(short)f2b(acc[et][0]), (short)f2b(acc[et][1]),
                  (short)f2b(acc[et][2]), (short)f2b(acc[et][3])};
    *(short4v*)(orow + et * 16) = st;
  }
}

// ---------------- mamba: fused causal conv+SiLU -> x-projection MFMA; writes xc + dbl ----------------
__global__ __launch_bounds__(256) void k_xproj(const unsigned short* __restrict__ xz,
                                               const float* __restrict__ cw, const float* __restrict__ cb,
                                               const unsigned short* __restrict__ xwbf,
                                               unsigned short* __restrict__ xcg,
                                               float* __restrict__ dbl) {
  __shared__ unsigned short xis[67 * 264];
  int blk = blockIdx.x;
  int b = blk >> 2;
  int tq = blk & 3;
  int t0 = tq * 64;
  int tid = threadIdx.x;

  const short8 ZV = {0, 0, 0, 0, 0, 0, 0, 0};
  for (int idx = tid; idx < 2144; idx += 256) {
    int row = idx >> 5, cu = idx & 31;
    int t = t0 - 3 + row;
    short8 v = ZV;
    if (t >= 0) v = *(const short8*)(xz + ((size_t)b * 256 + t) * 512 + cu * 8);
    *(short8*)(xis + row * 264 + cu * 8) = v;
  }
  __syncthreads();

  int cu = tid & 31;
  int rb = tid >> 5;
  int c8 = cu * 8;
  float wl[4][8], bl[8];
#pragma unroll
  for (int j = 0; j < 8; ++j) {
    float4 w4 = *(const float4*)&cw[(c8 + j) * 4];
    wl[0][j] = w4.x; wl[1][j] = w4.y; wl[2][j] = w4.z; wl[3][j] = w4.w;
    bl[j] = cb[c8 + j];
  }

  short8 vv[4];
#pragma unroll
  for (int s = 0; s < 4; ++s) {
    int r = rb + s * 8;
    float acc[8];
#pragma unroll
    for (int j = 0; j < 8; ++j) acc[j] = bl[j];
#pragma unroll
    for (int k = 0; k < 4; ++k) {
      short8 u8 = *(const short8*)(xis + (r + k) * 264 + c8);
#pragma unroll
      for (int j = 0; j < 8; ++j) acc[j] += b2f((unsigned short)u8[j]) * wl[k][j];
    }
#pragma unroll
    for (int j = 0; j < 8; ++j)
      vv[s][j] = (short)f2b(acc[j] / (1.0f + __expf(-acc[j])));
    *(short8*)(xcg + ((size_t)b * 256 + t0 + r) * 256 + c8) = vv[s];
  }
  __syncthreads();
#pragma unroll
  for (int s = 0; s < 4; ++s)
    *(short8*)(xis + (rb + s * 8) * 264 + c8) = vv[s];

#pragma unroll
  for (int s = 0; s < 4; ++s) {
    int r = 32 + rb + s * 8;
    float acc[8];
#pragma unroll
    for (int j = 0; j < 8; ++j) acc[j] = bl[j];
#pragma unroll
    for (int k = 0; k < 4; ++k) {
      short8 u8 = *(const short8*)(xis + (r + k) * 264 + c8);
#pragma unroll
      for (int j = 0; j < 8; ++j) acc[j] += b2f((unsigned short)u8[j]) * wl[k][j];
    }
#pragma unroll
    for (int j = 0; j < 8; ++j)
      vv[s][j] = (short)f2b(acc[j] / (1.0f + __expf(-acc[j])));
    *(short8*)(xcg + ((size_t)b * 256 + t0 + r) * 256 + c8) = vv[s];
  }
  __syncthreads();
#pragma unroll
  for (int s = 0; s < 4; ++s)
    *(short8*)(xis + (32 + rb + s * 8) * 264 + c8) = vv[s];
  __syncthreads();

  int wv = tid >> 6, ln = tid & 15, q = (tid >> 4) & 3;
  int tl = wv * 16 + ln;
  short8 bfrag[8];
#pragma unroll
  for (int kc = 0; kc < 8; ++kc)
    bfrag[kc] = *(const short8*)(xis + tl * 264 + kc * 32 + q * 8);
  float4v acc[3];
#pragma unroll
  for (int et = 0; et < 3; ++et) acc[et] = (float4v){0.f, 0.f, 0.f, 0.f};
#pragma unroll
  for (int et = 0; et < 3; ++et) {
    const unsigned short* arow = xwbf + (size_t)(et * 16 + ln) * 256 + q * 8;
#pragma unroll
    for (int kc = 0; kc < 8; ++kc) {
      short8 af = *(const short8*)(arow + kc * 32);
      acc[et] = __builtin_amdgcn_mfma_f32_16x16x32_bf16(af, bfrag[kc], acc[et], 0, 0, 0);
    }
  }
  float* drow = dbl + ((size_t)b * 256 + t0 + tl) * 40;
#pragma unroll
  for (int et = 0; et < 3; ++et)
#pragma unroll
    for (int r = 0; r < 4; ++r) {
      int k = et * 16 + q * 4 + r;
      if (k < 40) drow[k] = acc[et][r];
    }
}

// ---------------- mamba: fused dt + selective scan + y-finalize ----------------
__global__ __launch_bounds__(128) void k_scan2(const float* __restrict__ dbl,
                                               const unsigned short* __restrict__ xc,
                                               const unsigned short* __restrict__ xz,
                                               const float* __restrict__ Alog,
                                               const float* __restrict__ dtw, const float* __restrict__ dtbv,
                                               const float* __restrict__ Dp, unsigned short* __restrict__ y) {
  __shared__ float ds[32][40];
  __shared__ float dxs[32][32][4];
  __shared__ float yl[32][32];
  __shared__ float dtwL[32][8];
  __shared__ float dtbL[32];
  __shared__ float DpL[32];

  int b = blockIdx.x >> 3;
  int c0 = (blockIdx.x & 7) * 32;
  int tid = threadIdx.x;

  for (int idx = tid; idx < 256; idx += 128) dtwL[idx >> 3][idx & 7] = dtw[(c0 + (idx >> 3)) * 8 + (idx & 7)];
  if (tid < 32) { dtbL[tid] = dtbv[c0 + tid]; DpL[tid] = Dp[c0 + tid]; }

  int lane = tid & 63;
  int wv = tid >> 6;
  int c_loc = wv * 16 + (lane >> 2);
  int c = c0 + c_loc;
  int sblk = (lane & 3) * 4;

  float4 Al = *(const float4*)&Alog[c * 16 + sblk];
  float A[4] = {-__expf(Al.x), -__expf(Al.y), -__expf(Al.z), -__expf(Al.w)};
  float h[4] = {0.f, 0.f, 0.f, 0.f};

  const float* dbp = dbl + (size_t)b * 10240;
  const unsigned short* xcp = xc + (size_t)b * 65536;
  const unsigned short* xzp = xz + (size_t)b * 131072;
  unsigned short* yp = y + (size_t)b * 65536;

  for (int chk = 0; chk < 8; ++chk) {
    int t0c = chk * 32;
    for (int idx = tid; idx < 1280; idx += 128) ((float*)ds)[idx] = dbp[t0c * 40 + idx];
    for (int idx = tid; idx < 512; idx += 128) {
      int t = idx >> 4, cc2 = (idx & 15) * 2;
      ushort2 xv = *(const ushort2*)&xcp[(size_t)(t0c + t) * 256 + c0 + cc2];
      ushort2 zv = *(const ushort2*)&xzp[(size_t)(t0c + t) * 512 + 256 + c0 + cc2];
      dxs[t][cc2][1] = b2f(xv.x);
      dxs[t][cc2 + 1][1] = b2f(xv.y);
      dxs[t][cc2][2] = b2f(zv.x);
      dxs[t][cc2 + 1][2] = b2f(zv.y);
    }
    __syncthreads();
    for (int idx = tid; idx < 1024; idx += 128) {
      int t = idx >> 5, cc = idx & 31;
      const float* dr = ds[t];
      const float* wr = dtwL[cc];
      float acc = dtbL[cc];
#pragma unroll
      for (int j = 0; j < 8; ++j) acc += wr[j] * dr[j];
      dxs[t][cc][0] = (acc > 20.0f) ? acc : __logf(1.0f + __expf(acc));
    }
    __syncthreads();
#pragma unroll 4
    for (int t = 0; t < 32; ++t) {
      float4 dx = *(const float4*)&dxs[t][c_loc][0];
      float4 Bv = *(const float4*)&ds[t][8 + sblk];
      float4 Cv = *(const float4*)&ds[t][24 + sblk];
      float dtv = dx.x;
      float bx = dtv * dx.y;
      h[0] = __expf(dtv * A[0]) * h[0] + Bv.x * bx;
      h[1] = __expf(dtv * A[1]) * h[1] + Bv.y * bx;
      h[2] = __expf(dtv * A[2]) * h[2] + Bv.z * bx;
      h[3] = __expf(dtv * A[3]) * h[3] + Bv.w * bx;
      float p = h[0] * Cv.x;
      p = fmaf(h[1], Cv.y, p);
      p = fmaf(h[2], Cv.z, p);
      p = fmaf(h[3], Cv.w, p);
      p += qxor1(p);
      p += qxor2(p);
      if ((lane & 3) == 0) yl[t][c_loc] = p;
    }
    __syncthreads();
    for (int idx = tid; idx < 512; idx += 128) {
      int t = idx >> 4, cc2 = (idx & 15) * 2;
      float p0 = yl[t][cc2], p1 = yl[t][cc2 + 1];
      float x0 = dxs[t][cc2][1], x1 = dxs[t][cc2 + 1][1];
      float z0 = dxs[t][cc2][2], z1 = dxs[t][cc2 + 1][2];
      float s0 = z0 / (1.0f + __expf(-z0));
      float s1 = z1 / (1.0f + __expf(-z1));
      ushort2 o = {f2b((p0 + DpL[cc2] * x0) * s0), f2b((p1 + DpL[cc2 + 1] * x1) * s1)};
      *(ushort2*)&yp[(size_t)(t0c + t) * 256 + c0 + cc2] = o;
    }
    __syncthreads();
  }
}

// ---------------- mamba: MFMA out-projection + residual + LayerNorm, zero-LDS ----------------
__global__ __launch_bounds__(128) void k_outln(const unsigned short* __restrict__ yb,
                                               const unsigned short* __restrict__ owbf,
                                               float* __restrict__ xe2, unsigned short* __restrict__ xe2bf,
                                               const float* __restrict__ g, const float* __restrict__ bb) {
  int blk = blockIdx.x;
  int b = blk >> 3;
  int t0 = (blk & 7) * 32;
  int tid = threadIdx.x;
  int wv = tid >> 6, ln = tid & 15, q = (tid >> 4) & 3;
  int t = t0 + wv * 16 + ln;

  const unsigned short* yrow = yb + ((size_t)b * 256 + t) * 256 + q * 8;
  short8 bfrag[8];
#pragma unroll
  for (int kc = 0; kc < 8; ++kc) bfrag[kc] = *(const short8*)(yrow + kc * 32);

  float4v acc[8];
#pragma unroll
  for (int et = 0; et < 8; ++et) acc[et] = (float4v){0.f, 0.f, 0.f, 0.f};
#pragma unroll
  for (int et = 0; et < 8; ++et) {
    const unsigned short* arow = owbf + (size_t)(et * 16 + ln) * 256 + q * 8;
#pragma unroll
    for (int kc = 0; kc < 8; ++kc) {
      short8 af = *(const short8*)(arow + kc * 32);
      acc[et] = __builtin_amdgcn_mfma_f32_16x16x32_bf16(af, bfrag[kc], acc[et], 0, 0, 0);
    }
  }

  float* xrow = xe2 + ((size_t)b * 256 + t) * 128;
  float vals[8][4];
  float s1 = 0.f, s2 = 0.f;
#pragma unroll
  for (int et = 0; et < 8; ++et) {
    float4 res = *(const float4*)(xrow + et * 16 + q * 4);
    float rv[4] = {res.x, res.y, res.z, res.w};
#pragma unroll
    for (int r = 0; r < 4; ++r) {
      float v = acc[et][r] + rv[r];
      vals[et][r] = v;
      s1 += v;
      s2 += v * v;
    }
  }
  s1 += __shfl_xor(s1, 16, 64);
  s1 += __shfl_xor(s1, 32, 64);
  s2 += __shfl_xor(s2, 16, 64);
  s2 += __shfl_xor(s2, 32, 64);
  float mu = s1 * (1.0f / 128.0f);
  float rs = rsqrtf(s2 * (1.0f / 128.0f) - mu * mu + 1e-5f);

  unsigned short* brow = xe2bf + ((size_t)b * 256 + t) * 128;
#pragma unroll
  for (int et = 0; et < 8; ++et) {
    int d = et * 16 + q * 4;
    float4 g4 = *(const float4*)(g + d);
    float4 b4 = *(const float4*)(bb + d);
    float o0 = (vals[et][0] - mu) * rs * g4.x + b4.x;
    float o1 = (vals[et][1] - mu) * rs * g4.y + b4.y;
    float o2 = (vals[et][2] - mu) * rs * g4.z + b4.z;
    float o3 = (vals[et][3] - mu) * rs * g4.w + b4.w;
    float4 of = {o0, o1, o2, o3};
    *(float4*)(xrow + d) = of;
    short4v ob = {(short)f2b(o0), (short)f2b(o1), (short)f2b(o2), (short)f2b(o3)};
    *(short4v*)(brow + d) = ob;
  }
}

// ---------------- xflat transpose (+bf16 copy, + pred bias init) ----------------
__global__ __launch_bounds__(256) void k_xflat(const float* __restrict__ xe2, float* __restrict__ out,
                                               unsigned short* __restrict__ outbf,
                                               const float* __restrict__ fcb, float* __restrict__ pred) {
  int b = blockIdx.x >> 5;
  int blk = blockIdx.x & 31;
  int t0 = (blk >> 2) * 32, d0 = (blk & 3) * 32;
  __shared__ float tile[32][33];
  int tid = threadIdx.x;
  if (blockIdx.x == 0) {
    for (int i = tid; i < 1152; i += 256) pred[i] = fcb[i % 18];
  }
#pragma unroll
  for (int q = 0; q < 4; ++q) {
    int t = (tid >> 5) + q * 8, dd = tid & 31;
    tile[t][dd] = xe2[(size_t)b * 32768 + (size_t)(t0 + t) * 128 + d0 + dd];
  }
  __syncthreads();
#pragma unroll
  for (int q = 0; q < 4; ++q) {
    int dd = (tid >> 5) + q * 8, t = tid & 31;
    float v = tile[t][dd];
    size_t o = (size_t)b * 32768 + (size_t)(d0 + dd) * 256 + t0 + t;
    out[o] = v;
    outbf[o] = f2b(v);
  }
}

// ---------------- final FC via MFMA ----------------
__global__ __launch_bounds__(256) void k_fc(const unsigned short* __restrict__ xflatbf,
                                            const unsigned short* __restrict__ fwbf,
                                            float* __restrict__ pred) {
  int kb = blockIdx.x;
  int k0 = kb * 256;
  int tid = threadIdx.x;
  int wv = tid >> 6, ln = tid & 15, q = (tid >> 4) & 3;
  int b = wv * 16 + ln;
  const unsigned short* xrow = xflatbf + (size_t)b * 32768 + k0 + q * 8;
  float4v acc[2];
  acc[0] = (float4v){0.f, 0.f, 0.f, 0.f};
  acc[1] = (float4v){0.f, 0.f, 0.f, 0.f};
#pragma unroll
  for (int kc = 0; kc < 8; ++kc) {
    short8 bfrag = *(const short8*)(xrow + kc * 32);
#pragma unroll
    for (int et = 0; et < 2; ++et) {
      short8 af = *(const short8*)(fwbf + (size_t)(et * 16 + ln) * 32768 + k0 + kc * 32 + q * 8);
      acc[et] = __builtin_amdgcn_mfma_f32_16x16x32_bf16(af, bfrag, acc[et], 0, 0, 0);
    }
  }
#pragma unroll
  for (int et = 0; et < 2; ++et)
#pragma unroll
    for (int r = 0; r < 4; ++r) {
      int c = et * 16 + q * 4 + r;
      if (c < 18) atomicAdd(&pred[b * 18 + c], acc[et][r]);
    }
}

extern "C" void kernel_launch(void* const* d_in, const int* in_sizes, int n_in,
                              void* d_out, int out_size, void* d_ws, size_t ws_size,
                              hipStream_t stream) {
  (void)in_sizes; (void)n_in; (void)out_size; (void)ws_size;
  const float* inp    = (const float*)d_in[0];
  const float* emb_w  = (const float*)d_in[1];
  const float* emb_b  = (const float*)d_in[2];
  const float* dw_w   = (const float*)d_in[3];
  const float* dw_b   = (const float*)d_in[4];
  const float* pw_w   = (const float*)d_in[5];
  const float* pw_b   = (const float*)d_in[6];
  const float* se_w1  = (const float*)d_in[7];
  const float* se_b1  = (const float*)d_in[8];
  const float* se_w2  = (const float*)d_in[9];
  const float* se_b2  = (const float*)d_in[10];
  const float* in_w   = (const float*)d_in[11];
  const float* conv_w = (const float*)d_in[12];
  const float* conv_b = (const float*)d_in[13];
  const float* xp_w   = (const float*)d_in[14];
  const float* dt_w   = (const float*)d_in[15];
  const float* dt_b   = (const float*)d_in[16];
  const float* Alog   = (const float*)d_in[17];
  const float* Dp     = (const float*)d_in[18];
  const float* out_w  = (const float*)d_in[19];
  const float* ln_g   = (const float*)d_in[20];
  const float* ln_b   = (const float*)d_in[21];
  const float* fc_w   = (const float*)d_in[22];
  const float* fc_b   = (const float*)d_in[23];

  char* ws = (char*)d_ws;
  unsigned short* U0 = (unsigned short*)(ws);
  unsigned short* xz = (unsigned short*)(ws);                 // after reduce2
  unsigned short* xc = (unsigned short*)(ws + 33554432);
  unsigned short* yb = (unsigned short*)(ws + 50331648);
  float* xe2 = (float*)(ws + 100663296);
  unsigned short* xflatbf = (unsigned short*)(ws + 109051904);
  unsigned short* fwbf = (unsigned short*)(ws + 113246208);
  float* dbl = (float*)(ws + 150994944);
  unsigned short* xe2bf = (unsigned short*)(ws + 153616384);

  float* xflat = (float*)d_out;
  float* pred  = xflat + (size_t)64 * 32768;
  unsigned short* pwbf  = (unsigned short*)d_out;   // weight scratch until k_xflat
  unsigned short* inwbf = pwbf + 49152;
  unsigned short* owbf  = inwbf + 131072;
  unsigned short* xwbf  = owbf + 65536;
  unsigned short* ewbf  = xwbf + 24576;

  hipFuncSetAttribute((const void*)k_mega, hipFuncAttributeMaxDynamicSharedMemorySize, MEGA_LDS);

  k_cvt<<<1072, 256, 0, stream>>>(pw_w, in_w, out_w, xp_w, emb_w, pwbf);
  k_emb<<<768, 256, 0, stream>>>(inp, ewbf, emb_b, U0);

  k_mega<<<768, 512, MEGA_LDS, stream>>>(U0, dw_w, dw_b, pwbf, pw_b,
                                         se_w1, se_b1, se_w2, se_b2, U0);

  k_reduce2<<<1024, 256, 0, stream>>>(U0, xe2, xe2bf);
  k_cvt2<<<4096, 256, 0, stream>>>(fc_w, fwbf);

  for (int i = 0; i < 2; ++i) {
    k_inproj<<<512, 256, 0, stream>>>(xe2bf, inwbf + i * 65536, xz);
    k_xproj<<<256, 256, 0, stream>>>(xz, conv_w + i * 1024, conv_b + i * 256,
                                     xwbf + i * 12288, xc, dbl);
    k_scan2<<<512, 128, 0, stream>>>(dbl, xc, xz, Alog + i * 4096,
                                     dt_w + i * 2048, dt_b + i * 256, Dp + i * 256, yb);
    k_outln<<<512, 128, 0, stream>>>(yb, owbf + i * 32768, xe2, xe2bf,
                                     ln_g + i * 128, ln_b + i * 128);
  }

  k_xflat<<<2048, 256, 0, stream>>>(xe2, xflat, xflatbf, fc_b, pred);
  k_fc<<<128, 256, 0, stream>>>(xflatbf, fwbf, pred);
}